// Round 15
// baseline (638.162 us; speedup 1.0000x reference)
//
#include <hip/hip_runtime.h>
#include <hip/hip_bf16.h>

#define N_NODES 50000
#define N_EDGES 800000
#define D_IN    16
#define D_HID   64
#define D_OUT   16
#define NCHUNK  ((N_NODES + 255) / 256)   // 196 scan chunks
#define TMAX    100352                    // >= worst-case padded tile count

typedef __hip_bfloat16 bf16;
typedef _Float16 f16;
typedef _Float16 f16x8 __attribute__((ext_vector_type(8)));
typedef float    f32x4 __attribute__((ext_vector_type(4)));
typedef _Float16 f16x8a __attribute__((ext_vector_type(8), may_alias));

__device__ __forceinline__ float b2f(bf16 v) { return __bfloat162float(v); }
__device__ __forceinline__ int clampn(int v) {
    return v < 0 ? 0 : (v >= N_NODES ? N_NODES - 1 : v);
}
__device__ __forceinline__ float rdf(const void* p, long i, int isbf) {
    return isbf ? b2f(((const bf16*)p)[i]) : ((const float*)p)[i];
}
__device__ __forceinline__ f16x8 relu8(f16x8 v) {
#pragma unroll
    for (int j = 0; j < 8; j++) v[j] = v[j] > (f16)0 ? v[j] : (f16)0;
    return v;
}

__global__ void k_detect(const unsigned short* __restrict__ xw,
                         const int* __restrict__ ei, int* __restrict__ flags)
{
    if (threadIdx.x == 0) {
        int inband = 0;
        for (int j = 0; j < 256; j++) {
            unsigned short w = xw[2 * j];
            int e = (w >> 7) & 0xFF;
            if ((w & 0x7FFF) == 0 || (e >= 100 && e <= 140)) inband++;
        }
        flags[0] = (inband >= 192) ? 1 : 0;
        int z = 1;
        for (int j = 1; j < 128; j += 2) z &= (ei[j] == 0) ? 1 : 0;
        flags[1] = z;
    }
}

__global__ __launch_bounds__(256) void k_zero_i(int* __restrict__ p, int n)
{
    int i = blockIdx.x * 256 + threadIdx.x;
    if (i < n) p[i] = 0;
}

__global__ __launch_bounds__(256) void k_zero4(float4* __restrict__ p, int n4)
{
    int i = blockIdx.x * 256 + threadIdx.x;
    if (i < n4) p[i] = (float4){0.f, 0.f, 0.f, 0.f};
}

// ---- counting sort of edges by dst + padded tile list (once per launch) ----
__global__ __launch_bounds__(256) void k_hist(const int* __restrict__ flags,
                                              const int* __restrict__ eidx,
                                              int* __restrict__ hist)
{
    int e = blockIdx.x * 256 + threadIdx.x;
    if (e >= N_EDGES) return;
    const int strd = flags[1] ? 2 : 1;
    const long dbase = flags[1] ? (long)(2 * N_EDGES) : (long)N_EDGES;
    int d = clampn(eidx[dbase + (long)e * strd]);
    atomicAdd(&hist[d], 1);
}

// generic 3-stage exclusive scan over N_NODES bins.
// mode 0: value = in[i];  mode 1: value = ceil(in[i]/16)  (tile counts)
__global__ __launch_bounds__(256) void k_scan1(const int* __restrict__ in,
                                               int* __restrict__ bsum, int mode)
{
    __shared__ int red[256];
    int i = blockIdx.x * 256 + threadIdx.x;
    int v = (i < N_NODES) ? in[i] : 0;
    if (mode) v = (v + 15) >> 4;
    red[threadIdx.x] = v;
    __syncthreads();
    for (int d = 128; d > 0; d >>= 1) {
        if (threadIdx.x < d) red[threadIdx.x] += red[threadIdx.x + d];
        __syncthreads();
    }
    if (threadIdx.x == 0) bsum[blockIdx.x] = red[0];
}

__global__ __launch_bounds__(256) void k_scan2(const int* __restrict__ bsum,
                                               int* __restrict__ boff,
                                               int* __restrict__ total_out)
{
    __shared__ int s[256];
    const int t = threadIdx.x;
    s[t] = (t < NCHUNK) ? bsum[t] : 0;
    __syncthreads();
    for (int d = 1; d < 256; d <<= 1) {
        int v = (t >= d) ? s[t - d] : 0;
        __syncthreads();
        s[t] += v;
        __syncthreads();
    }
    if (t < NCHUNK) boff[t] = (t == 0) ? 0 : s[t - 1];
    if (t == NCHUNK - 1) total_out[0] = s[t];
}

__global__ __launch_bounds__(256) void k_scan3(const int* __restrict__ in,
                                               const int* __restrict__ boff,
                                               int* __restrict__ off,
                                               int* __restrict__ cursor, int mode)
{
    __shared__ int s[256];
    const int t = threadIdx.x;
    int i = blockIdx.x * 256 + t;
    int v = (i < N_NODES) ? in[i] : 0;
    if (mode) v = (v + 15) >> 4;
    s[t] = v;
    __syncthreads();
    for (int d = 1; d < 256; d <<= 1) {
        int u = (t >= d) ? s[t - d] : 0;
        __syncthreads();
        s[t] += u;
        __syncthreads();
    }
    if (i < N_NODES) {
        int ex = boff[blockIdx.x] + s[t] - v;   // exclusive prefix
        off[i] = ex; cursor[i] = ex;
    }
}

// scatter: src indices in dst-sorted order
__global__ __launch_bounds__(256) void k_scatter(const int* __restrict__ flags,
                                                 const int* __restrict__ eidx,
                                                 int* __restrict__ cursor,
                                                 int* __restrict__ ssrc)
{
    int e = blockIdx.x * 256 + threadIdx.x;
    if (e >= N_EDGES) return;
    const int strd = flags[1] ? 2 : 1;
    const long dbase = flags[1] ? (long)(2 * N_EDGES) : (long)N_EDGES;
    int d = clampn(eidx[dbase + (long)e * strd]);
    int s = clampn(eidx[(long)e * strd]);
    int pos = atomicAdd(&cursor[d], 1);
    ssrc[pos] = s;
}

// tile metadata: tmeta[t] = node | (valid<<20)   (~1.43 entries per node)
__global__ __launch_bounds__(256) void k_tmeta(const int* __restrict__ hist,
                                               const int* __restrict__ toff,
                                               int* __restrict__ tmeta)
{
    int n = blockIdx.x * 256 + threadIdx.x;
    if (n >= N_NODES) return;
    int dg = hist[n];
    if (dg == 0) return;
    int t0 = toff[n], nt = (dg + 15) >> 4;
    for (int j = 0; j < nt; j++)
        tmeta[t0 + j] = n | (min(16, dg - 16 * j) << 20);
}

// padded src fill: one thread per tile slot (coalesced), last edge replicated
__global__ __launch_bounds__(256) void k_fill(const int* __restrict__ hist,
                                              const int* __restrict__ off,
                                              const int* __restrict__ toff,
                                              const int* __restrict__ totalp,
                                              const int* __restrict__ tmeta,
                                              const int* __restrict__ ssrc,
                                              int* __restrict__ spad)
{
    int idx = blockIdx.x * 256 + threadIdx.x;
    int t = idx >> 4, i = idx & 15;
    if (t >= totalp[0]) return;
    int n = tmeta[t] & 0xFFFFF;
    int j = t - toff[n];
    int dg = hist[n];
    spad[idx] = ssrc[off[n] + min(16 * j + i, dg - 1)];
}

__global__ __launch_bounds__(256) void k_lin_in(const int* __restrict__ flags,
                                                const void* __restrict__ x,
                                                const void* __restrict__ w,
                                                const void* __restrict__ b,
                                                float* __restrict__ h)
{
    int idx = blockIdx.x * 256 + threadIdx.x;
    if (idx >= N_NODES * D_HID) return;
    const int isbf = flags[0];
    int n = idx >> 6, c = idx & 63;
    float acc = rdf(b, c, isbf);
#pragma unroll
    for (int i = 0; i < D_IN; i++)
        acc += rdf(x, (long)n * D_IN + i, isbf) * rdf(w, (long)i * D_HID + c, isbf);
    h[idx] = acc;
}

// ---------------------------------------------------------------------------
// Node projection (round-10 verified): Psrc = H@W0[0:64], Pdst = H@W0[64:]+b0
// ---------------------------------------------------------------------------
#define W0P_ST 136
#define HP_ST   72

__global__ __launch_bounds__(256) void k_proj(
    const int* __restrict__ flags, const float* __restrict__ hin,
    const void* __restrict__ gw0, const void* __restrict__ gb0,
    f16* __restrict__ psrc, f16* __restrict__ pdst, int kblk)
{
    __shared__ f16 w0T[64 * W0P_ST];
    __shared__ f16 hL_s[4][16 * HP_ST];

    const int tid  = threadIdx.x;
    const int isbf = flags[0];

    const long wb0 = (long)kblk * 2 * D_HID * D_HID;
    for (int i = tid; i < 2 * D_HID * D_HID; i += 256) {
        int n = i >> 7, k = i & 127;
        w0T[n * W0P_ST + k] = (f16)rdf(gw0, wb0 + (long)k * 64 + n, isbf);
    }
    __syncthreads();

    const int wv = tid >> 6, ln = tid & 63;
    const int lm = ln & 15, quad = ln >> 4;
    f16* hL = hL_s[wv];

    const int g = blockIdx.x * 4 + wv;
    if (g >= N_NODES / 16) return;
    const int n0 = g * 16;

#pragma unroll
    for (int i = 0; i < 16; i++) {
        int idx = i * 64 + ln;
        hL[(idx >> 6) * HP_ST + (idx & 63)] = (f16)hin[(long)n0 * 64 + idx];
    }

    f16x8 a[2];
#pragma unroll
    for (int c = 0; c < 2; c++)
        a[c] = *(const f16x8a*)&hL[lm * HP_ST + c * 32 + quad * 8];

    f32x4 accS[4], accD[4];
#pragma unroll
    for (int q = 0; q < 4; q++) {
        float bd = rdf(gb0, (long)kblk * 64 + q * 16 + lm, isbf);
        accS[q] = (f32x4){0.f, 0.f, 0.f, 0.f};
        accD[q] = (f32x4){bd, bd, bd, bd};
    }
#pragma unroll
    for (int c = 0; c < 2; c++)
#pragma unroll
        for (int q = 0; q < 4; q++) {
            f16x8 bs = *(const f16x8a*)&w0T[(q * 16 + lm) * W0P_ST + c * 32 + quad * 8];
            f16x8 bd = *(const f16x8a*)&w0T[(q * 16 + lm) * W0P_ST + 64 + c * 32 + quad * 8];
            accS[q] = __builtin_amdgcn_mfma_f32_16x16x32_f16(a[c], bs, accS[q], 0, 0, 0);
            accD[q] = __builtin_amdgcn_mfma_f32_16x16x32_f16(a[c], bd, accD[q], 0, 0, 0);
        }
#pragma unroll
    for (int q = 0; q < 4; q++)
#pragma unroll
        for (int r = 0; r < 4; r++) {
            long o = (long)(n0 + quad * 4 + r) * 64 + q * 16 + lm;
            psrc[o] = (f16)accS[q][r];
            pdst[o] = (f16)accD[q][r];
        }
}

// ---------------------------------------------------------------------------
// Uniform tile-list aggregation, register pipeline depth 2 (round-14 verified).
// ROUND-15: __launch_bounds__(256,4) raises the VGPR cap to 128 so the
// compiler keeps the 64 weight-fragment VGPRs register-resident instead of
// re-reading 16 ds_read_b128 per tile (round-14: VGPR_Count=88 proved the
// weights were LDS-resident; LDS-issue arithmetic ~45 of the 74 us).
// ---------------------------------------------------------------------------
#define Y_ST  72
#define W1_ST 72

__global__ __launch_bounds__(256, 4) void k_edge_tile(
    const int* __restrict__ flags,
    const int* __restrict__ ssrc_pad, const int* __restrict__ tmeta,
    const int* __restrict__ toff,
    const f16* __restrict__ psrc, const f16* __restrict__ pdst,
    float* __restrict__ hout,
    const void* __restrict__ gw1, const void* __restrict__ gb1,
    const void* __restrict__ gw2, const void* __restrict__ gb2, int kblk)
{
    __shared__ f16 w1T[64 * W1_ST];          // 9216 B
    __shared__ f16 w2T[64 * W1_ST];          // 9216 B
    __shared__ f16 y_s[4][16 * Y_ST];        // 9216 B

    const int tid  = threadIdx.x;
    const int isbf = flags[0];

    const long wb1 = (long)kblk * D_HID * D_HID;
    for (int i = tid; i < D_HID * D_HID; i += 256) {
        int n = i >> 6, k = i & 63;
        w1T[n * W1_ST + k] = (f16)rdf(gw1, wb1 + (long)k * 64 + n, isbf);
        w2T[n * W1_ST + k] = (f16)rdf(gw2, wb1 + (long)k * 64 + n, isbf);
    }
    __syncthreads();

    const int wv = tid >> 6, ln = tid & 63;
    const int lm = ln & 15, quad = ln >> 4;

    f16x8 bw1[2][4], bw2[2][4];
#pragma unroll
    for (int c = 0; c < 2; c++)
#pragma unroll
        for (int q = 0; q < 4; q++) {
            bw1[c][q] = *(const f16x8a*)&w1T[(q * 16 + lm) * W1_ST + c * 32 + quad * 8];
            bw2[c][q] = *(const f16x8a*)&w2T[(q * 16 + lm) * W1_ST + c * 32 + quad * 8];
        }
    float bias1[4], bias2[4];
#pragma unroll
    for (int q = 0; q < 4; q++) {
        bias1[q] = rdf(gb1, (long)kblk * 64 + q * 16 + lm, isbf);
        bias2[q] = rdf(gb2, (long)kblk * 64 + q * 16 + lm, isbf);
    }

    f16* yb = y_s[wv];
    const int sub = ln & 7, eh = ln >> 3;

    const int T  = toff[N_NODES];
    const int W  = gridDim.x * 4;
    const int gw = blockIdx.x * 4 + wv;
    const int t0 = (int)((long)gw * T / W);
    const int t1 = (int)((long)(gw + 1) * T / W);
    if (t0 >= t1) return;

    // ---- pipeline prologue ----
    int tc1 = min(t0 + 1, T - 1);
    int m0 = tmeta[t0], m1 = tmeta[tc1];
    int s1a = ssrc_pad[tc1 * 16 + eh], s1b = ssrc_pad[tc1 * 16 + 8 + eh];
    int s0a = ssrc_pad[t0 * 16 + eh],  s0b = ssrc_pad[t0 * 16 + 8 + eh];
    f16x8 ps0a = *(const f16x8a*)&psrc[(long)s0a * 64 + sub * 8];
    f16x8 ps0b = *(const f16x8a*)&psrc[(long)s0b * 64 + sub * 8];
    f16x8 pd0  = *(const f16x8a*)&pdst[(long)(m0 & 0xFFFFF) * 64 + sub * 8];

    float accn[4] = {0.f, 0.f, 0.f, 0.f};

    for (int tt = t0; tt < t1; tt++) {
        // ---- prefetch (registers only) ----
        const int t2 = min(tt + 2, T - 1);
        int m2  = tmeta[t2];
        int s2a = ssrc_pad[t2 * 16 + eh], s2b = ssrc_pad[t2 * 16 + 8 + eh];
        f16x8 ps1a = *(const f16x8a*)&psrc[(long)s1a * 64 + sub * 8];
        f16x8 ps1b = *(const f16x8a*)&psrc[(long)s1b * 64 + sub * 8];
        f16x8 pd1  = *(const f16x8a*)&pdst[(long)(m1 & 0xFFFFF) * 64 + sub * 8];

        // ---- compute tile tt ----
        const int valid = m0 >> 20;
        *(f16x8a*)&yb[eh * Y_ST + sub * 8]       = relu8(ps0a + pd0);
        *(f16x8a*)&yb[(8 + eh) * Y_ST + sub * 8] = relu8(ps0b + pd0);

        f16x8 a1[2];
#pragma unroll
        for (int c = 0; c < 2; c++)
            a1[c] = *(const f16x8a*)&yb[lm * Y_ST + c * 32 + quad * 8];
        f32x4 acc[4];
#pragma unroll
        for (int q = 0; q < 4; q++)
            acc[q] = (f32x4){bias1[q], bias1[q], bias1[q], bias1[q]};
#pragma unroll
        for (int c = 0; c < 2; c++)
#pragma unroll
            for (int q = 0; q < 4; q++)
                acc[q] = __builtin_amdgcn_mfma_f32_16x16x32_f16(a1[c], bw1[c][q], acc[q], 0, 0, 0);
#pragma unroll
        for (int q = 0; q < 4; q++)
#pragma unroll
            for (int r = 0; r < 4; r++)
                yb[(quad * 4 + r) * Y_ST + q * 16 + lm] = (f16)fmaxf(acc[q][r], 0.f);

        f16x8 a2[2];
#pragma unroll
        for (int c = 0; c < 2; c++)
            a2[c] = *(const f16x8a*)&yb[lm * Y_ST + c * 32 + quad * 8];
#pragma unroll
        for (int q = 0; q < 4; q++)
            acc[q] = (f32x4){bias2[q], bias2[q], bias2[q], bias2[q]};
#pragma unroll
        for (int c = 0; c < 2; c++)
#pragma unroll
            for (int q = 0; q < 4; q++)
                acc[q] = __builtin_amdgcn_mfma_f32_16x16x32_f16(a2[c], bw2[c][q], acc[q], 0, 0, 0);

#pragma unroll
        for (int q = 0; q < 4; q++)
#pragma unroll
            for (int r = 0; r < 4; r++)
                if (quad * 4 + r < valid) accn[q] += acc[q][r];

        // ---- flush on node change (wave-uniform branch) ----
        const int curn  = m0 & 0xFFFFF;
        const int nextn = (tt + 1 < t1) ? (m1 & 0xFFFFF) : -1;
        if (nextn != curn) {
#pragma unroll
            for (int q = 0; q < 4; q++) {
                float v = accn[q];
                v += __shfl_xor(v, 16, 64);
                v += __shfl_xor(v, 32, 64);
                if (quad == 0) atomicAdd(&hout[(long)curn * 64 + q * 16 + lm], v);
                accn[q] = 0.f;
            }
        }

        // ---- rotate pipeline ----
        m0 = m1; m1 = m2;
        s1a = s2a; s1b = s2b;
        ps0a = ps1a; ps0b = ps1b; pd0 = pd1;
    }
}

__global__ __launch_bounds__(256) void k_lin_out(const int* __restrict__ flags,
                                                 const float* __restrict__ h,
                                                 const void* __restrict__ w,
                                                 const void* __restrict__ b,
                                                 float* __restrict__ out)
{
    int idx = blockIdx.x * 256 + threadIdx.x;
    if (idx >= N_NODES * D_OUT) return;
    const int isbf = flags[0];
    int n = idx >> 4, c = idx & 15;
    float acc = rdf(b, c, isbf);
    const float* hr = h + (long)n * D_HID;
#pragma unroll
    for (int i = 0; i < D_HID; i++) acc += hr[i] * rdf(w, (long)i * D_OUT + c, isbf);
    out[idx] = acc;
}

extern "C" void kernel_launch(void* const* d_in, const int* in_sizes, int n_in,
                              void* d_out, int out_size, void* d_ws, size_t ws_size,
                              hipStream_t stream)
{
    const void* x    = d_in[0];
    const int*  ei   = (const int*)d_in[2];
    const void* liw  = d_in[3];
    const void* lib  = d_in[4];
    const void* w0   = d_in[5];
    const void* b0   = d_in[6];
    const void* w1   = d_in[7];
    const void* b1   = d_in[8];
    const void* w2   = d_in[9];
    const void* b2   = d_in[10];
    const void* low  = d_in[11];
    const void* lob  = d_in[12];
    float* out = (float*)d_out;

    // ws (~36.8 MB, under proven 38.7 MB)
    char* wp = (char*)d_ws;
    int*   flags  = (int*)wp;                 wp += 256;
    float* hA     = (float*)wp;               wp += (size_t)N_NODES * D_HID * 4;
    f16*   Psrc   = (f16*)wp;                 wp += (size_t)N_NODES * D_HID * 2;
    f16*   Pdst   = (f16*)wp;                 wp += (size_t)N_NODES * D_HID * 2;
    int*   hist   = (int*)wp;                 wp += (size_t)N_NODES * 4;
    int*   off    = (int*)wp;                 wp += ((size_t)N_NODES + 1) * 4;
    int*   cursor = (int*)wp;                 wp += (size_t)N_NODES * 4;
    int*   toff   = (int*)wp;                 wp += ((size_t)N_NODES + 1) * 4;
    int*   tcur   = (int*)wp;                 wp += (size_t)N_NODES * 4;
    int*   bsum   = (int*)wp;                 wp += 256 * 4;
    int*   boff   = (int*)wp;                 wp += 256 * 4;
    int*   ssrc   = (int*)wp;                 wp += (size_t)N_EDGES * 4;
    int*   tmeta  = (int*)wp;                 wp += (size_t)TMAX * 4;
    int*   spad   = (int*)wp;                 // TMAX*16 ints = 6.4 MB

    const int HN = N_NODES * D_HID;
    const int gH = (HN + 255) / 256;
    const int gE = (N_EDGES + 255) / 256;
    const int gN = (N_NODES + 255) / 256;

    k_detect<<<1, 64, 0, stream>>>((const unsigned short*)x, ei, flags);

    // one-time: dst-sort + padded tile list (reused by all 4 graph blocks)
    k_zero_i<<<gN, 256, 0, stream>>>(hist, N_NODES);
    k_hist<<<gE, 256, 0, stream>>>(flags, ei, hist);
    k_scan1<<<NCHUNK, 256, 0, stream>>>(hist, bsum, 0);
    k_scan2<<<1, 256, 0, stream>>>(bsum, boff, off + N_NODES);
    k_scan3<<<NCHUNK, 256, 0, stream>>>(hist, boff, off, cursor, 0);
    k_scatter<<<gE, 256, 0, stream>>>(flags, ei, cursor, ssrc);
    k_scan1<<<NCHUNK, 256, 0, stream>>>(hist, bsum, 1);
    k_scan2<<<1, 256, 0, stream>>>(bsum, boff, toff + N_NODES);
    k_scan3<<<NCHUNK, 256, 0, stream>>>(hist, boff, toff, tcur, 1);
    k_tmeta<<<gN, 256, 0, stream>>>(hist, toff, tmeta);
    k_fill<<<(TMAX * 16) / 256, 256, 0, stream>>>(hist, off, toff, toff + N_NODES,
                                                  tmeta, ssrc, spad);

    k_lin_in<<<gH, 256, 0, stream>>>(flags, x, liw, lib, hA);

    for (int k = 0; k < 4; k++) {
        k_proj<<<(N_NODES / 16 + 3) / 4, 256, 0, stream>>>(flags, hA, w0, b0, Psrc, Pdst, k);
        k_zero4<<<(HN / 4 + 255) / 256, 256, 0, stream>>>((float4*)hA, HN / 4);
        k_edge_tile<<<1024, 256, 0, stream>>>(flags, spad, tmeta, toff,
                                              Psrc, Pdst, hA, w1, b1, w2, b2, k);
    }

    k_lin_out<<<(N_NODES * D_OUT + 255) / 256, 256, 0, stream>>>(flags, hA, low, lob, out);
}

// Round 16
// 574.198 us; speedup vs baseline: 1.1114x; 1.1114x over previous
//
#include <hip/hip_runtime.h>
#include <hip/hip_bf16.h>

#define N_NODES 50000
#define N_EDGES 800000
#define D_IN    16
#define D_HID   64
#define D_OUT   16
#define NCHUNK  ((N_NODES + 255) / 256)   // 196 scan chunks
#define TMAX    100352                    // >= worst-case padded tile count

typedef __hip_bfloat16 bf16;
typedef _Float16 f16;
typedef _Float16 f16x8 __attribute__((ext_vector_type(8)));
typedef float    f32x4 __attribute__((ext_vector_type(4)));
typedef _Float16 f16x8a __attribute__((ext_vector_type(8), may_alias));

__device__ __forceinline__ float b2f(bf16 v) { return __bfloat162float(v); }
__device__ __forceinline__ int clampn(int v) {
    return v < 0 ? 0 : (v >= N_NODES ? N_NODES - 1 : v);
}
__device__ __forceinline__ float rdf(const void* p, long i, int isbf) {
    return isbf ? b2f(((const bf16*)p)[i]) : ((const float*)p)[i];
}
__device__ __forceinline__ f16x8 relu8(f16x8 v) {
#pragma unroll
    for (int j = 0; j < 8; j++) v[j] = v[j] > (f16)0 ? v[j] : (f16)0;
    return v;
}

__global__ void k_detect(const unsigned short* __restrict__ xw,
                         const int* __restrict__ ei, int* __restrict__ flags)
{
    if (threadIdx.x == 0) {
        int inband = 0;
        for (int j = 0; j < 256; j++) {
            unsigned short w = xw[2 * j];
            int e = (w >> 7) & 0xFF;
            if ((w & 0x7FFF) == 0 || (e >= 100 && e <= 140)) inband++;
        }
        flags[0] = (inband >= 192) ? 1 : 0;
        int z = 1;
        for (int j = 1; j < 128; j += 2) z &= (ei[j] == 0) ? 1 : 0;
        flags[1] = z;
    }
}

__global__ __launch_bounds__(256) void k_zero_i(int* __restrict__ p, int n)
{
    int i = blockIdx.x * 256 + threadIdx.x;
    if (i < n) p[i] = 0;
}

// ---- counting sort of edges by dst + padded tile list (once per launch) ----
__global__ __launch_bounds__(256) void k_hist(const int* __restrict__ flags,
                                              const int* __restrict__ eidx,
                                              int* __restrict__ hist)
{
    int e = blockIdx.x * 256 + threadIdx.x;
    if (e >= N_EDGES) return;
    const int strd = flags[1] ? 2 : 1;
    const long dbase = flags[1] ? (long)(2 * N_EDGES) : (long)N_EDGES;
    int d = clampn(eidx[dbase + (long)e * strd]);
    atomicAdd(&hist[d], 1);
}

// generic 3-stage exclusive scan over N_NODES bins.
// mode 0: value = in[i];  mode 1: value = ceil(in[i]/16)  (tile counts)
__global__ __launch_bounds__(256) void k_scan1(const int* __restrict__ in,
                                               int* __restrict__ bsum, int mode)
{
    __shared__ int red[256];
    int i = blockIdx.x * 256 + threadIdx.x;
    int v = (i < N_NODES) ? in[i] : 0;
    if (mode) v = (v + 15) >> 4;
    red[threadIdx.x] = v;
    __syncthreads();
    for (int d = 128; d > 0; d >>= 1) {
        if (threadIdx.x < d) red[threadIdx.x] += red[threadIdx.x + d];
        __syncthreads();
    }
    if (threadIdx.x == 0) bsum[blockIdx.x] = red[0];
}

__global__ __launch_bounds__(256) void k_scan2(const int* __restrict__ bsum,
                                               int* __restrict__ boff,
                                               int* __restrict__ total_out)
{
    __shared__ int s[256];
    const int t = threadIdx.x;
    s[t] = (t < NCHUNK) ? bsum[t] : 0;
    __syncthreads();
    for (int d = 1; d < 256; d <<= 1) {
        int v = (t >= d) ? s[t - d] : 0;
        __syncthreads();
        s[t] += v;
        __syncthreads();
    }
    if (t < NCHUNK) boff[t] = (t == 0) ? 0 : s[t - 1];
    if (t == NCHUNK - 1) total_out[0] = s[t];
}

__global__ __launch_bounds__(256) void k_scan3(const int* __restrict__ in,
                                               const int* __restrict__ boff,
                                               int* __restrict__ off,
                                               int* __restrict__ cursor, int mode)
{
    __shared__ int s[256];
    const int t = threadIdx.x;
    int i = blockIdx.x * 256 + t;
    int v = (i < N_NODES) ? in[i] : 0;
    if (mode) v = (v + 15) >> 4;
    s[t] = v;
    __syncthreads();
    for (int d = 1; d < 256; d <<= 1) {
        int u = (t >= d) ? s[t - d] : 0;
        __syncthreads();
        s[t] += u;
        __syncthreads();
    }
    if (i < N_NODES) {
        int ex = boff[blockIdx.x] + s[t] - v;   // exclusive prefix
        off[i] = ex; cursor[i] = ex;
    }
}

// scatter: src indices in dst-sorted order
__global__ __launch_bounds__(256) void k_scatter(const int* __restrict__ flags,
                                                 const int* __restrict__ eidx,
                                                 int* __restrict__ cursor,
                                                 int* __restrict__ ssrc)
{
    int e = blockIdx.x * 256 + threadIdx.x;
    if (e >= N_EDGES) return;
    const int strd = flags[1] ? 2 : 1;
    const long dbase = flags[1] ? (long)(2 * N_EDGES) : (long)N_EDGES;
    int d = clampn(eidx[dbase + (long)e * strd]);
    int s = clampn(eidx[(long)e * strd]);
    int pos = atomicAdd(&cursor[d], 1);
    ssrc[pos] = s;
}

// tile metadata: tmeta[t] = node | (valid<<20)
__global__ __launch_bounds__(256) void k_tmeta(const int* __restrict__ hist,
                                               const int* __restrict__ toff,
                                               int* __restrict__ tmeta)
{
    int n = blockIdx.x * 256 + threadIdx.x;
    if (n >= N_NODES) return;
    int dg = hist[n];
    if (dg == 0) return;
    int t0 = toff[n], nt = (dg + 15) >> 4;
    for (int j = 0; j < nt; j++)
        tmeta[t0 + j] = n | (min(16, dg - 16 * j) << 20);
}

// padded src fill: one thread per tile slot (coalesced), last edge replicated
__global__ __launch_bounds__(256) void k_fill(const int* __restrict__ hist,
                                              const int* __restrict__ off,
                                              const int* __restrict__ toff,
                                              const int* __restrict__ totalp,
                                              const int* __restrict__ tmeta,
                                              const int* __restrict__ ssrc,
                                              int* __restrict__ spad)
{
    int idx = blockIdx.x * 256 + threadIdx.x;
    int t = idx >> 4, i = idx & 15;
    if (t >= totalp[0]) return;
    int n = tmeta[t] & 0xFFFFF;
    int j = t - toff[n];
    int dg = hist[n];
    spad[idx] = ssrc[off[n] + min(16 * j + i, dg - 1)];
}

__global__ __launch_bounds__(256) void k_lin_in(const int* __restrict__ flags,
                                                const void* __restrict__ x,
                                                const void* __restrict__ w,
                                                const void* __restrict__ b,
                                                float* __restrict__ h)
{
    int idx = blockIdx.x * 256 + threadIdx.x;
    if (idx >= N_NODES * D_HID) return;
    const int isbf = flags[0];
    int n = idx >> 6, c = idx & 63;
    float acc = rdf(b, c, isbf);
#pragma unroll
    for (int i = 0; i < D_IN; i++)
        acc += rdf(x, (long)n * D_IN + i, isbf) * rdf(w, (long)i * D_HID + c, isbf);
    h[idx] = acc;
}

// ---------------------------------------------------------------------------
// Node projection + hA zeroing: Psrc = H@W0[0:64], Pdst = H@W0[64:]+b0, then
// zero the H rows just read (each wave owns 16 rows exclusively). Saves the
// separate k_zero4 dispatch. hio is read+zeroed via ONE pointer (no restrict
// aliasing issue).
// ---------------------------------------------------------------------------
#define W0P_ST 136
#define HP_ST   72

__global__ __launch_bounds__(256) void k_proj(
    const int* __restrict__ flags, float* hio,
    const void* __restrict__ gw0, const void* __restrict__ gb0,
    f16* __restrict__ psrc, f16* __restrict__ pdst, int kblk)
{
    __shared__ f16 w0T[64 * W0P_ST];
    __shared__ f16 hL_s[4][16 * HP_ST];

    const int tid  = threadIdx.x;
    const int isbf = flags[0];

    const long wb0 = (long)kblk * 2 * D_HID * D_HID;
    for (int i = tid; i < 2 * D_HID * D_HID; i += 256) {
        int n = i >> 7, k = i & 127;
        w0T[n * W0P_ST + k] = (f16)rdf(gw0, wb0 + (long)k * 64 + n, isbf);
    }
    __syncthreads();

    const int wv = tid >> 6, ln = tid & 63;
    const int lm = ln & 15, quad = ln >> 4;
    f16* hL = hL_s[wv];

    const int g = blockIdx.x * 4 + wv;
    if (g >= N_NODES / 16) return;
    const int n0 = g * 16;

    // stage 16 node rows f32->f16 (coalesced), then zero them for the
    // upcoming aggregation pass (wave-private rows, program order safe)
#pragma unroll
    for (int i = 0; i < 16; i++) {
        int idx = i * 64 + ln;
        hL[(idx >> 6) * HP_ST + (idx & 63)] = (f16)hio[(long)n0 * 64 + idx];
    }
#pragma unroll
    for (int i = 0; i < 16; i++)
        hio[(long)n0 * 64 + i * 64 + ln] = 0.f;

    f16x8 a[2];
#pragma unroll
    for (int c = 0; c < 2; c++)
        a[c] = *(const f16x8a*)&hL[lm * HP_ST + c * 32 + quad * 8];

    f32x4 accS[4], accD[4];
#pragma unroll
    for (int q = 0; q < 4; q++) {
        float bd = rdf(gb0, (long)kblk * 64 + q * 16 + lm, isbf);
        accS[q] = (f32x4){0.f, 0.f, 0.f, 0.f};
        accD[q] = (f32x4){bd, bd, bd, bd};
    }
#pragma unroll
    for (int c = 0; c < 2; c++)
#pragma unroll
        for (int q = 0; q < 4; q++) {
            f16x8 bs = *(const f16x8a*)&w0T[(q * 16 + lm) * W0P_ST + c * 32 + quad * 8];
            f16x8 bd = *(const f16x8a*)&w0T[(q * 16 + lm) * W0P_ST + 64 + c * 32 + quad * 8];
            accS[q] = __builtin_amdgcn_mfma_f32_16x16x32_f16(a[c], bs, accS[q], 0, 0, 0);
            accD[q] = __builtin_amdgcn_mfma_f32_16x16x32_f16(a[c], bd, accD[q], 0, 0, 0);
        }
#pragma unroll
    for (int q = 0; q < 4; q++)
#pragma unroll
        for (int r = 0; r < 4; r++) {
            long o = (long)(n0 + quad * 4 + r) * 64 + q * 16 + lm;
            psrc[o] = (f16)accS[q][r];
            pdst[o] = (f16)accD[q][r];
        }
}

// ---------------------------------------------------------------------------
// Uniform tile-list aggregation, PAIR-ILP (round-16): each wave processes two
// independent tiles per iteration in separate y buffers, phase-interleaved so
// tile B's DS ops fill tile A's ~120-cyc LDS latency stalls (R15 analysis:
// ~640 cyc/tile dominated by the serial LDS chain; MFMA floor is only ~78).
// Default launch bounds (R15 lesson: min-occupancy arg shrinks VGPRs).
// Register pipeline: data for tiles tt..tt+3, meta/indices to tt+5.
// ---------------------------------------------------------------------------
#define Y_ST  72
#define W1_ST 72

__global__ __launch_bounds__(256) void k_edge_tile(
    const int* __restrict__ flags,
    const int* __restrict__ ssrc_pad, const int* __restrict__ tmeta,
    const int* __restrict__ toff,
    const f16* __restrict__ psrc, const f16* __restrict__ pdst,
    float* __restrict__ hout,
    const void* __restrict__ gw1, const void* __restrict__ gb1,
    const void* __restrict__ gw2, const void* __restrict__ gb2, int kblk)
{
    __shared__ f16 w1T[64 * W1_ST];          //  9216 B
    __shared__ f16 w2T[64 * W1_ST];          //  9216 B
    __shared__ f16 y_s[4][2][16 * Y_ST];     // 18432 B  (total 36,864)

    const int tid  = threadIdx.x;
    const int isbf = flags[0];

    const long wb1 = (long)kblk * D_HID * D_HID;
    for (int i = tid; i < D_HID * D_HID; i += 256) {
        int n = i >> 6, k = i & 63;
        w1T[n * W1_ST + k] = (f16)rdf(gw1, wb1 + (long)k * 64 + n, isbf);
        w2T[n * W1_ST + k] = (f16)rdf(gw2, wb1 + (long)k * 64 + n, isbf);
    }
    __syncthreads();

    const int wv = tid >> 6, ln = tid & 63;
    const int lm = ln & 15, quad = ln >> 4;

    f16x8 bw1[2][4], bw2[2][4];
#pragma unroll
    for (int c = 0; c < 2; c++)
#pragma unroll
        for (int q = 0; q < 4; q++) {
            bw1[c][q] = *(const f16x8a*)&w1T[(q * 16 + lm) * W1_ST + c * 32 + quad * 8];
            bw2[c][q] = *(const f16x8a*)&w2T[(q * 16 + lm) * W1_ST + c * 32 + quad * 8];
        }
    float bias1[4], bias2[4];
#pragma unroll
    for (int q = 0; q < 4; q++) {
        bias1[q] = rdf(gb1, (long)kblk * 64 + q * 16 + lm, isbf);
        bias2[q] = rdf(gb2, (long)kblk * 64 + q * 16 + lm, isbf);
    }

    f16* yA = y_s[wv][0];
    f16* yB = y_s[wv][1];
    const int sub = ln & 7, eh = ln >> 3;

    const int T  = toff[N_NODES];
    const int W  = gridDim.x * 4;
    const int gw = blockIdx.x * 4 + wv;
    const int t0 = (int)((long)gw * T / W);
    const int t1 = (int)((long)(gw + 1) * T / W);
    if (t0 >= t1) return;

    // ---- pipeline prologue: meta tt..tt+3, data tt..tt+1, idx tt+2..tt+3
    int tcA = t0, tcB = min(t0 + 1, T - 1);
    int tc2 = min(t0 + 2, T - 1), tc3 = min(t0 + 3, T - 1);
    int m0 = tmeta[tcA], m1 = tmeta[tcB], m2 = tmeta[tc2], m3 = tmeta[tc3];
    int s2a = ssrc_pad[tc2 * 16 + eh], s2b = ssrc_pad[tc2 * 16 + 8 + eh];
    int s3a = ssrc_pad[tc3 * 16 + eh], s3b = ssrc_pad[tc3 * 16 + 8 + eh];
    int s0a = ssrc_pad[tcA * 16 + eh], s0b = ssrc_pad[tcA * 16 + 8 + eh];
    int s1a = ssrc_pad[tcB * 16 + eh], s1b = ssrc_pad[tcB * 16 + 8 + eh];
    f16x8 ps0a = *(const f16x8a*)&psrc[(long)s0a * 64 + sub * 8];
    f16x8 ps0b = *(const f16x8a*)&psrc[(long)s0b * 64 + sub * 8];
    f16x8 pd0  = *(const f16x8a*)&pdst[(long)(m0 & 0xFFFFF) * 64 + sub * 8];
    f16x8 ps1a = *(const f16x8a*)&psrc[(long)s1a * 64 + sub * 8];
    f16x8 ps1b = *(const f16x8a*)&psrc[(long)s1b * 64 + sub * 8];
    f16x8 pd1  = *(const f16x8a*)&pdst[(long)(m1 & 0xFFFFF) * 64 + sub * 8];

    float accn[4] = {0.f, 0.f, 0.f, 0.f};

    for (int tt = t0; tt < t1; tt += 2) {
        // ---- prefetch meta/indices for tiles tt+4, tt+5 ----
        const int tc4 = min(tt + 4, T - 1), tc5 = min(tt + 5, T - 1);
        int m4 = tmeta[tc4], m5 = tmeta[tc5];
        int s4a = ssrc_pad[tc4 * 16 + eh], s4b = ssrc_pad[tc4 * 16 + 8 + eh];
        int s5a = ssrc_pad[tc5 * 16 + eh], s5b = ssrc_pad[tc5 * 16 + 8 + eh];
        // ---- load gather data for tiles tt+2, tt+3 ----
        f16x8 ps2a = *(const f16x8a*)&psrc[(long)s2a * 64 + sub * 8];
        f16x8 ps2b = *(const f16x8a*)&psrc[(long)s2b * 64 + sub * 8];
        f16x8 pd2  = *(const f16x8a*)&pdst[(long)(m2 & 0xFFFFF) * 64 + sub * 8];
        f16x8 ps3a = *(const f16x8a*)&psrc[(long)s3a * 64 + sub * 8];
        f16x8 ps3b = *(const f16x8a*)&psrc[(long)s3b * 64 + sub * 8];
        f16x8 pd3  = *(const f16x8a*)&pdst[(long)(m3 & 0xFFFFF) * 64 + sub * 8];

        const int hasB = (tt + 1 < t1);
        const int v0 = m0 >> 20;
        const int v1 = hasB ? (m1 >> 20) : 0;

        // ---- layer 0 (both tiles) ----
        *(f16x8a*)&yA[eh * Y_ST + sub * 8]       = relu8(ps0a + pd0);
        *(f16x8a*)&yA[(8 + eh) * Y_ST + sub * 8] = relu8(ps0b + pd0);
        *(f16x8a*)&yB[eh * Y_ST + sub * 8]       = relu8(ps1a + pd1);
        *(f16x8a*)&yB[(8 + eh) * Y_ST + sub * 8] = relu8(ps1b + pd1);

        // ---- layer 1 (both) ----
        f16x8 a1A[2], a1B[2];
#pragma unroll
        for (int c = 0; c < 2; c++) {
            a1A[c] = *(const f16x8a*)&yA[lm * Y_ST + c * 32 + quad * 8];
            a1B[c] = *(const f16x8a*)&yB[lm * Y_ST + c * 32 + quad * 8];
        }
        f32x4 accA[4], accB[4];
#pragma unroll
        for (int q = 0; q < 4; q++) {
            accA[q] = (f32x4){bias1[q], bias1[q], bias1[q], bias1[q]};
            accB[q] = (f32x4){bias1[q], bias1[q], bias1[q], bias1[q]};
        }
#pragma unroll
        for (int c = 0; c < 2; c++)
#pragma unroll
            for (int q = 0; q < 4; q++) {
                accA[q] = __builtin_amdgcn_mfma_f32_16x16x32_f16(a1A[c], bw1[c][q], accA[q], 0, 0, 0);
                accB[q] = __builtin_amdgcn_mfma_f32_16x16x32_f16(a1B[c], bw1[c][q], accB[q], 0, 0, 0);
            }
#pragma unroll
        for (int q = 0; q < 4; q++)
#pragma unroll
            for (int r = 0; r < 4; r++) {
                yA[(quad * 4 + r) * Y_ST + q * 16 + lm] = (f16)fmaxf(accA[q][r], 0.f);
                yB[(quad * 4 + r) * Y_ST + q * 16 + lm] = (f16)fmaxf(accB[q][r], 0.f);
            }

        // ---- layer 2 (both) ----
        f16x8 a2A[2], a2B[2];
#pragma unroll
        for (int c = 0; c < 2; c++) {
            a2A[c] = *(const f16x8a*)&yA[lm * Y_ST + c * 32 + quad * 8];
            a2B[c] = *(const f16x8a*)&yB[lm * Y_ST + c * 32 + quad * 8];
        }
#pragma unroll
        for (int q = 0; q < 4; q++) {
            accA[q] = (f32x4){bias2[q], bias2[q], bias2[q], bias2[q]};
            accB[q] = (f32x4){bias2[q], bias2[q], bias2[q], bias2[q]};
        }
#pragma unroll
        for (int c = 0; c < 2; c++)
#pragma unroll
            for (int q = 0; q < 4; q++) {
                accA[q] = __builtin_amdgcn_mfma_f32_16x16x32_f16(a2A[c], bw2[c][q], accA[q], 0, 0, 0);
                accB[q] = __builtin_amdgcn_mfma_f32_16x16x32_f16(a2B[c], bw2[c][q], accB[q], 0, 0, 0);
            }

        // ---- accumulate + flush tile A ----
#pragma unroll
        for (int q = 0; q < 4; q++)
#pragma unroll
            for (int r = 0; r < 4; r++)
                if (quad * 4 + r < v0) accn[q] += accA[q][r];
        {
            const int curn = m0 & 0xFFFFF;
            const int nxt  = hasB ? (m1 & 0xFFFFF) : -1;
            if (nxt != curn) {
#pragma unroll
                for (int q = 0; q < 4; q++) {
                    float v = accn[q];
                    v += __shfl_xor(v, 16, 64);
                    v += __shfl_xor(v, 32, 64);
                    if (quad == 0) atomicAdd(&hout[(long)curn * 64 + q * 16 + lm], v);
                    accn[q] = 0.f;
                }
            }
        }
        // ---- accumulate + flush tile B ----
        if (hasB) {
#pragma unroll
            for (int q = 0; q < 4; q++)
#pragma unroll
                for (int r = 0; r < 4; r++)
                    if (quad * 4 + r < v1) accn[q] += accB[q][r];
            const int curn = m1 & 0xFFFFF;
            const int nxt  = (tt + 2 < t1) ? (m2 & 0xFFFFF) : -1;
            if (nxt != curn) {
#pragma unroll
                for (int q = 0; q < 4; q++) {
                    float v = accn[q];
                    v += __shfl_xor(v, 16, 64);
                    v += __shfl_xor(v, 32, 64);
                    if (quad == 0) atomicAdd(&hout[(long)curn * 64 + q * 16 + lm], v);
                    accn[q] = 0.f;
                }
            }
        }

        // ---- rotate pipeline ----
        m0 = m2; m1 = m3; m2 = m4; m3 = m5;
        s2a = s4a; s2b = s4b; s3a = s5a; s3b = s5b;
        ps0a = ps2a; ps0b = ps2b; pd0 = pd2;
        ps1a = ps3a; ps1b = ps3b; pd1 = pd3;
    }
}

__global__ __launch_bounds__(256) void k_lin_out(const int* __restrict__ flags,
                                                 const float* __restrict__ h,
                                                 const void* __restrict__ w,
                                                 const void* __restrict__ b,
                                                 float* __restrict__ out)
{
    int idx = blockIdx.x * 256 + threadIdx.x;
    if (idx >= N_NODES * D_OUT) return;
    const int isbf = flags[0];
    int n = idx >> 4, c = idx & 15;
    float acc = rdf(b, c, isbf);
    const float* hr = h + (long)n * D_HID;
#pragma unroll
    for (int i = 0; i < D_HID; i++) acc += hr[i] * rdf(w, (long)i * D_OUT + c, isbf);
    out[idx] = acc;
}

extern "C" void kernel_launch(void* const* d_in, const int* in_sizes, int n_in,
                              void* d_out, int out_size, void* d_ws, size_t ws_size,
                              hipStream_t stream)
{
    const void* x    = d_in[0];
    const int*  ei   = (const int*)d_in[2];
    const void* liw  = d_in[3];
    const void* lib  = d_in[4];
    const void* w0   = d_in[5];
    const void* b0   = d_in[6];
    const void* w1   = d_in[7];
    const void* b1   = d_in[8];
    const void* w2   = d_in[9];
    const void* b2   = d_in[10];
    const void* low  = d_in[11];
    const void* lob  = d_in[12];
    float* out = (float*)d_out;

    // ws (~36.8 MB, under proven 38.7 MB)
    char* wp = (char*)d_ws;
    int*   flags  = (int*)wp;                 wp += 256;
    float* hA     = (float*)wp;               wp += (size_t)N_NODES * D_HID * 4;
    f16*   Psrc   = (f16*)wp;                 wp += (size_t)N_NODES * D_HID * 2;
    f16*   Pdst   = (f16*)wp;                 wp += (size_t)N_NODES * D_HID * 2;
    int*   hist   = (int*)wp;                 wp += (size_t)N_NODES * 4;
    int*   off    = (int*)wp;                 wp += ((size_t)N_NODES + 1) * 4;
    int*   cursor = (int*)wp;                 wp += (size_t)N_NODES * 4;
    int*   toff   = (int*)wp;                 wp += ((size_t)N_NODES + 1) * 4;
    int*   tcur   = (int*)wp;                 wp += (size_t)N_NODES * 4;
    int*   bsum   = (int*)wp;                 wp += 256 * 4;
    int*   boff   = (int*)wp;                 wp += 256 * 4;
    int*   ssrc   = (int*)wp;                 wp += (size_t)N_EDGES * 4;
    int*   tmeta  = (int*)wp;                 wp += (size_t)TMAX * 4;
    int*   spad   = (int*)wp;                 // TMAX*16 ints = 6.4 MB

    const int HN = N_NODES * D_HID;
    const int gH = (HN + 255) / 256;
    const int gE = (N_EDGES + 255) / 256;
    const int gN = (N_NODES + 255) / 256;

    k_detect<<<1, 64, 0, stream>>>((const unsigned short*)x, ei, flags);

    // one-time: dst-sort + padded tile list (reused by all 4 graph blocks)
    k_zero_i<<<gN, 256, 0, stream>>>(hist, N_NODES);
    k_hist<<<gE, 256, 0, stream>>>(flags, ei, hist);
    k_scan1<<<NCHUNK, 256, 0, stream>>>(hist, bsum, 0);
    k_scan2<<<1, 256, 0, stream>>>(bsum, boff, off + N_NODES);
    k_scan3<<<NCHUNK, 256, 0, stream>>>(hist, boff, off, cursor, 0);
    k_scatter<<<gE, 256, 0, stream>>>(flags, ei, cursor, ssrc);
    k_scan1<<<NCHUNK, 256, 0, stream>>>(hist, bsum, 1);
    k_scan2<<<1, 256, 0, stream>>>(bsum, boff, toff + N_NODES);
    k_scan3<<<NCHUNK, 256, 0, stream>>>(hist, boff, toff, tcur, 1);
    k_tmeta<<<gN, 256, 0, stream>>>(hist, toff, tmeta);
    k_fill<<<(TMAX * 16) / 256, 256, 0, stream>>>(hist, off, toff, toff + N_NODES,
                                                  tmeta, ssrc, spad);

    k_lin_in<<<gH, 256, 0, stream>>>(flags, x, liw, lib, hA);

    for (int k = 0; k < 4; k++) {
        // k_proj reads hA, emits Psrc/Pdst, and zeroes hA for the aggregation
        k_proj<<<(N_NODES / 16 + 3) / 4, 256, 0, stream>>>(flags, hA, w0, b0, Psrc, Pdst, k);
        k_edge_tile<<<1024, 256, 0, stream>>>(flags, spad, tmeta, toff,
                                              Psrc, Pdst, hA, w1, b1, w2, b2, k);
    }

    k_lin_out<<<(N_NODES * D_OUT + 255) / 256, 256, 0, stream>>>(flags, hA, low, lob, out);
}

// Round 17
// 478.072 us; speedup vs baseline: 1.3349x; 1.2011x over previous
//
#include <hip/hip_runtime.h>
#include <hip/hip_bf16.h>

#define N_NODES 50000
#define N_EDGES 800000
#define D_IN    16
#define D_HID   64
#define D_OUT   16
#define NCHUNK  ((N_NODES + 255) / 256)   // 196 scan chunks
#define TMAX    100352                    // >= worst-case padded tile count

typedef __hip_bfloat16 bf16;
typedef _Float16 f16;
typedef _Float16 f16x8 __attribute__((ext_vector_type(8)));
typedef float    f32x4 __attribute__((ext_vector_type(4)));
typedef _Float16 f16x8a __attribute__((ext_vector_type(8), may_alias));

__device__ __forceinline__ float b2f(bf16 v) { return __bfloat162float(v); }
__device__ __forceinline__ int clampn(int v) {
    return v < 0 ? 0 : (v >= N_NODES ? N_NODES - 1 : v);
}
__device__ __forceinline__ float rdf(const void* p, long i, int isbf) {
    return isbf ? b2f(((const bf16*)p)[i]) : ((const float*)p)[i];
}
__device__ __forceinline__ f16x8 relu8(f16x8 v) {
#pragma unroll
    for (int j = 0; j < 8; j++) v[j] = v[j] > (f16)0 ? v[j] : (f16)0;
    return v;
}

__global__ void k_detect(const unsigned short* __restrict__ xw,
                         const int* __restrict__ ei, int* __restrict__ flags)
{
    if (threadIdx.x == 0) {
        int inband = 0;
        for (int j = 0; j < 256; j++) {
            unsigned short w = xw[2 * j];
            int e = (w >> 7) & 0xFF;
            if ((w & 0x7FFF) == 0 || (e >= 100 && e <= 140)) inband++;
        }
        flags[0] = (inband >= 192) ? 1 : 0;
        int z = 1;
        for (int j = 1; j < 128; j += 2) z &= (ei[j] == 0) ? 1 : 0;
        flags[1] = z;
    }
}

// ---------------------------------------------------------------------------
// One-time weight prep: pack MFMA B-fragments frag-major so every wave later
// reads its fragment as ONE contiguous 1KB coalesced load (L2/L3-resident).
// Slot map per graph-block kb (32 slots): [0,16)=W0 frag(c,q) slot=c*4+q
// (c in [0,4): k=c*32+quad*8+j covers K=128); [16,24)=W1 (c in [0,2));
// [24,32)=W2. Element j of slot = w[(c*32+quad*8+j)*64 + (q*16+lm)] — exactly
// the value the old per-dispatch LDS transpose produced (bit-identical f16).
// ---------------------------------------------------------------------------
__global__ __launch_bounds__(256) void k_wprep(const int* __restrict__ flags,
                                               const void* __restrict__ gw0,
                                               const void* __restrict__ gw1,
                                               const void* __restrict__ gw2,
                                               f16* __restrict__ wfrag)
{
    int idx = blockIdx.x * 256 + threadIdx.x;      // [0, 8192)
    if (idx >= 4 * 32 * 64) return;
    const int isbf = flags[0];
    int kb = idx >> 11, rem = idx & 2047;
    int slot = rem >> 6, lane = rem & 63;
    int lm = lane & 15, quad = lane >> 4;
    f16* outp = wfrag + (long)idx * 8;
    if (slot < 16) {
        int c = slot >> 2, q = slot & 3;
        long base = (long)kb * 2 * D_HID * D_HID;
#pragma unroll
        for (int j = 0; j < 8; j++)
            outp[j] = (f16)rdf(gw0, base + (long)(c * 32 + quad * 8 + j) * 64 + q * 16 + lm, isbf);
    } else {
        const void* gw = (slot < 24) ? gw1 : gw2;
        int s = (slot < 24) ? slot - 16 : slot - 24;
        int c = s >> 2, q = s & 3;
        long base = (long)kb * D_HID * D_HID;
#pragma unroll
        for (int j = 0; j < 8; j++)
            outp[j] = (f16)rdf(gw, base + (long)(c * 32 + quad * 8 + j) * 64 + q * 16 + lm, isbf);
    }
}

__global__ __launch_bounds__(256) void k_zero_i(int* __restrict__ p, int n)
{
    int i = blockIdx.x * 256 + threadIdx.x;
    if (i < n) p[i] = 0;
}

// ---- counting sort of edges by dst + padded tile list (once per launch) ----
__global__ __launch_bounds__(256) void k_hist(const int* __restrict__ flags,
                                              const int* __restrict__ eidx,
                                              int* __restrict__ hist)
{
    int e = blockIdx.x * 256 + threadIdx.x;
    if (e >= N_EDGES) return;
    const int strd = flags[1] ? 2 : 1;
    const long dbase = flags[1] ? (long)(2 * N_EDGES) : (long)N_EDGES;
    int d = clampn(eidx[dbase + (long)e * strd]);
    atomicAdd(&hist[d], 1);
}

// generic 3-stage exclusive scan over N_NODES bins.
// mode 0: value = in[i];  mode 1: value = ceil(in[i]/16)  (tile counts)
__global__ __launch_bounds__(256) void k_scan1(const int* __restrict__ in,
                                               int* __restrict__ bsum, int mode)
{
    __shared__ int red[256];
    int i = blockIdx.x * 256 + threadIdx.x;
    int v = (i < N_NODES) ? in[i] : 0;
    if (mode) v = (v + 15) >> 4;
    red[threadIdx.x] = v;
    __syncthreads();
    for (int d = 128; d > 0; d >>= 1) {
        if (threadIdx.x < d) red[threadIdx.x] += red[threadIdx.x + d];
        __syncthreads();
    }
    if (threadIdx.x == 0) bsum[blockIdx.x] = red[0];
}

__global__ __launch_bounds__(256) void k_scan2(const int* __restrict__ bsum,
                                               int* __restrict__ boff,
                                               int* __restrict__ total_out)
{
    __shared__ int s[256];
    const int t = threadIdx.x;
    s[t] = (t < NCHUNK) ? bsum[t] : 0;
    __syncthreads();
    for (int d = 1; d < 256; d <<= 1) {
        int v = (t >= d) ? s[t - d] : 0;
        __syncthreads();
        s[t] += v;
        __syncthreads();
    }
    if (t < NCHUNK) boff[t] = (t == 0) ? 0 : s[t - 1];
    if (t == NCHUNK - 1) total_out[0] = s[t];
}

__global__ __launch_bounds__(256) void k_scan3(const int* __restrict__ in,
                                               const int* __restrict__ boff,
                                               int* __restrict__ off,
                                               int* __restrict__ cursor, int mode)
{
    __shared__ int s[256];
    const int t = threadIdx.x;
    int i = blockIdx.x * 256 + t;
    int v = (i < N_NODES) ? in[i] : 0;
    if (mode) v = (v + 15) >> 4;
    s[t] = v;
    __syncthreads();
    for (int d = 1; d < 256; d <<= 1) {
        int u = (t >= d) ? s[t - d] : 0;
        __syncthreads();
        s[t] += u;
        __syncthreads();
    }
    if (i < N_NODES) {
        int ex = boff[blockIdx.x] + s[t] - v;   // exclusive prefix
        off[i] = ex; cursor[i] = ex;
    }
}

// scatter: src indices in dst-sorted order
__global__ __launch_bounds__(256) void k_scatter(const int* __restrict__ flags,
                                                 const int* __restrict__ eidx,
                                                 int* __restrict__ cursor,
                                                 int* __restrict__ ssrc)
{
    int e = blockIdx.x * 256 + threadIdx.x;
    if (e >= N_EDGES) return;
    const int strd = flags[1] ? 2 : 1;
    const long dbase = flags[1] ? (long)(2 * N_EDGES) : (long)N_EDGES;
    int d = clampn(eidx[dbase + (long)e * strd]);
    int s = clampn(eidx[(long)e * strd]);
    int pos = atomicAdd(&cursor[d], 1);
    ssrc[pos] = s;
}

// tile metadata: tmeta[t] = node | (valid<<20)
__global__ __launch_bounds__(256) void k_tmeta(const int* __restrict__ hist,
                                               const int* __restrict__ toff,
                                               int* __restrict__ tmeta)
{
    int n = blockIdx.x * 256 + threadIdx.x;
    if (n >= N_NODES) return;
    int dg = hist[n];
    if (dg == 0) return;
    int t0 = toff[n], nt = (dg + 15) >> 4;
    for (int j = 0; j < nt; j++)
        tmeta[t0 + j] = n | (min(16, dg - 16 * j) << 20);
}

// padded src fill: one thread per tile slot (coalesced), last edge replicated
__global__ __launch_bounds__(256) void k_fill(const int* __restrict__ hist,
                                              const int* __restrict__ off,
                                              const int* __restrict__ toff,
                                              const int* __restrict__ totalp,
                                              const int* __restrict__ tmeta,
                                              const int* __restrict__ ssrc,
                                              int* __restrict__ spad)
{
    int idx = blockIdx.x * 256 + threadIdx.x;
    int t = idx >> 4, i = idx & 15;
    if (t >= totalp[0]) return;
    int n = tmeta[t] & 0xFFFFF;
    int j = t - toff[n];
    int dg = hist[n];
    spad[idx] = ssrc[off[n] + min(16 * j + i, dg - 1)];
}

__global__ __launch_bounds__(256) void k_lin_in(const int* __restrict__ flags,
                                                const void* __restrict__ x,
                                                const void* __restrict__ w,
                                                const void* __restrict__ b,
                                                float* __restrict__ h)
{
    int idx = blockIdx.x * 256 + threadIdx.x;
    if (idx >= N_NODES * D_HID) return;
    const int isbf = flags[0];
    int n = idx >> 6, c = idx & 63;
    float acc = rdf(b, c, isbf);
#pragma unroll
    for (int i = 0; i < D_IN; i++)
        acc += rdf(x, (long)n * D_IN + i, isbf) * rdf(w, (long)i * D_HID + c, isbf);
    h[idx] = acc;
}

// ---------------------------------------------------------------------------
// Node projection + hA zeroing. ROUND-17: W0 fragments come straight from the
// pre-packed global wfrag buffer (coalesced 1KB/wave, L2-resident) — no LDS
// weight staging, no __syncthreads (hL is wave-private).
// ---------------------------------------------------------------------------
#define HP_ST 72

__global__ __launch_bounds__(256) void k_proj(
    const int* __restrict__ flags, float* hio,
    const f16* __restrict__ wfrag, const void* __restrict__ gb0,
    f16* __restrict__ psrc, f16* __restrict__ pdst, int kblk)
{
    __shared__ f16 hL_s[4][16 * HP_ST];     // 9216 B

    const int tid  = threadIdx.x;
    const int isbf = flags[0];
    const int wv = tid >> 6, ln = tid & 63;
    const int lm = ln & 15, quad = ln >> 4;
    f16* hL = hL_s[wv];

    const int g = blockIdx.x * 4 + wv;
    if (g >= N_NODES / 16) return;
    const int n0 = g * 16;

    const f16* wb = wfrag + (long)kblk * 32 * 64 * 8;

    // stage 16 node rows f32->f16 (coalesced), then zero them for the
    // upcoming aggregation pass (wave-private rows, program order safe)
#pragma unroll
    for (int i = 0; i < 16; i++) {
        int idx = i * 64 + ln;
        hL[(idx >> 6) * HP_ST + (idx & 63)] = (f16)hio[(long)n0 * 64 + idx];
    }
#pragma unroll
    for (int i = 0; i < 16; i++)
        hio[(long)n0 * 64 + i * 64 + ln] = 0.f;

    f16x8 a[2];
#pragma unroll
    for (int c = 0; c < 2; c++)
        a[c] = *(const f16x8a*)&hL[lm * HP_ST + c * 32 + quad * 8];

    f32x4 accS[4], accD[4];
#pragma unroll
    for (int q = 0; q < 4; q++) {
        float bd = rdf(gb0, (long)kblk * 64 + q * 16 + lm, isbf);
        accS[q] = (f32x4){0.f, 0.f, 0.f, 0.f};
        accD[q] = (f32x4){bd, bd, bd, bd};
    }
#pragma unroll
    for (int c = 0; c < 2; c++)
#pragma unroll
        for (int q = 0; q < 4; q++) {
            f16x8 bs = *(const f16x8a*)&wb[(((c + 0) * 4 + q) * 64 + ln) * 8];
            f16x8 bd = *(const f16x8a*)&wb[(((c + 2) * 4 + q) * 64 + ln) * 8];
            accS[q] = __builtin_amdgcn_mfma_f32_16x16x32_f16(a[c], bs, accS[q], 0, 0, 0);
            accD[q] = __builtin_amdgcn_mfma_f32_16x16x32_f16(a[c], bd, accD[q], 0, 0, 0);
        }
#pragma unroll
    for (int q = 0; q < 4; q++)
#pragma unroll
        for (int r = 0; r < 4; r++) {
            long o = (long)(n0 + quad * 4 + r) * 64 + q * 16 + lm;
            psrc[o] = (f16)accS[q][r];
            pdst[o] = (f16)accD[q][r];
        }
}

// ---------------------------------------------------------------------------
// Uniform tile-list aggregation, pair-ILP (R16-verified). ROUND-17: weight
// fragments load directly from the pre-packed global buffer (one coalesced
// 1KB read per frag per wave) — no LDS weight staging, no barrier; LDS drops
// 36,864 -> 18,432 B (y buffers only).
// ---------------------------------------------------------------------------
#define Y_ST 72

__global__ __launch_bounds__(256) void k_edge_tile(
    const int* __restrict__ flags,
    const int* __restrict__ ssrc_pad, const int* __restrict__ tmeta,
    const int* __restrict__ toff,
    const f16* __restrict__ psrc, const f16* __restrict__ pdst,
    float* __restrict__ hout,
    const f16* __restrict__ wfrag, const void* __restrict__ gb1,
    const void* __restrict__ gb2, int kblk)
{
    __shared__ f16 y_s[4][2][16 * Y_ST];     // 18432 B total

    const int tid  = threadIdx.x;
    const int isbf = flags[0];
    const int wv = tid >> 6, ln = tid & 63;
    const int lm = ln & 15, quad = ln >> 4;

    const f16* wb = wfrag + (long)kblk * 32 * 64 * 8;
    f16x8 bw1[2][4], bw2[2][4];
#pragma unroll
    for (int c = 0; c < 2; c++)
#pragma unroll
        for (int q = 0; q < 4; q++) {
            bw1[c][q] = *(const f16x8a*)&wb[((16 + c * 4 + q) * 64 + ln) * 8];
            bw2[c][q] = *(const f16x8a*)&wb[((24 + c * 4 + q) * 64 + ln) * 8];
        }
    float bias1[4], bias2[4];
#pragma unroll
    for (int q = 0; q < 4; q++) {
        bias1[q] = rdf(gb1, (long)kblk * 64 + q * 16 + lm, isbf);
        bias2[q] = rdf(gb2, (long)kblk * 64 + q * 16 + lm, isbf);
    }

    f16* yA = y_s[wv][0];
    f16* yB = y_s[wv][1];
    const int sub = ln & 7, eh = ln >> 3;

    const int T  = toff[N_NODES];
    const int W  = gridDim.x * 4;
    const int gw = blockIdx.x * 4 + wv;
    const int t0 = (int)((long)gw * T / W);
    const int t1 = (int)((long)(gw + 1) * T / W);
    if (t0 >= t1) return;

    // ---- pipeline prologue: meta tt..tt+3, data tt..tt+1, idx tt+2..tt+3
    int tcA = t0, tcB = min(t0 + 1, T - 1);
    int tc2 = min(t0 + 2, T - 1), tc3 = min(t0 + 3, T - 1);
    int m0 = tmeta[tcA], m1 = tmeta[tcB], m2 = tmeta[tc2], m3 = tmeta[tc3];
    int s2a = ssrc_pad[tc2 * 16 + eh], s2b = ssrc_pad[tc2 * 16 + 8 + eh];
    int s3a = ssrc_pad[tc3 * 16 + eh], s3b = ssrc_pad[tc3 * 16 + 8 + eh];
    int s0a = ssrc_pad[tcA * 16 + eh], s0b = ssrc_pad[tcA * 16 + 8 + eh];
    int s1a = ssrc_pad[tcB * 16 + eh], s1b = ssrc_pad[tcB * 16 + 8 + eh];
    f16x8 ps0a = *(const f16x8a*)&psrc[(long)s0a * 64 + sub * 8];
    f16x8 ps0b = *(const f16x8a*)&psrc[(long)s0b * 64 + sub * 8];
    f16x8 pd0  = *(const f16x8a*)&pdst[(long)(m0 & 0xFFFFF) * 64 + sub * 8];
    f16x8 ps1a = *(const f16x8a*)&psrc[(long)s1a * 64 + sub * 8];
    f16x8 ps1b = *(const f16x8a*)&psrc[(long)s1b * 64 + sub * 8];
    f16x8 pd1  = *(const f16x8a*)&pdst[(long)(m1 & 0xFFFFF) * 64 + sub * 8];

    float accn[4] = {0.f, 0.f, 0.f, 0.f};

    for (int tt = t0; tt < t1; tt += 2) {
        // ---- prefetch meta/indices for tiles tt+4, tt+5 ----
        const int tc4 = min(tt + 4, T - 1), tc5 = min(tt + 5, T - 1);
        int m4 = tmeta[tc4], m5 = tmeta[tc5];
        int s4a = ssrc_pad[tc4 * 16 + eh], s4b = ssrc_pad[tc4 * 16 + 8 + eh];
        int s5a = ssrc_pad[tc5 * 16 + eh], s5b = ssrc_pad[tc5 * 16 + 8 + eh];
        // ---- load gather data for tiles tt+2, tt+3 ----
        f16x8 ps2a = *(const f16x8a*)&psrc[(long)s2a * 64 + sub * 8];
        f16x8 ps2b = *(const f16x8a*)&psrc[(long)s2b * 64 + sub * 8];
        f16x8 pd2  = *(const f16x8a*)&pdst[(long)(m2 & 0xFFFFF) * 64 + sub * 8];
        f16x8 ps3a = *(const f16x8a*)&psrc[(long)s3a * 64 + sub * 8];
        f16x8 ps3b = *(const f16x8a*)&psrc[(long)s3b * 64 + sub * 8];
        f16x8 pd3  = *(const f16x8a*)&pdst[(long)(m3 & 0xFFFFF) * 64 + sub * 8];

        const int hasB = (tt + 1 < t1);
        const int v0 = m0 >> 20;
        const int v1 = hasB ? (m1 >> 20) : 0;

        // ---- layer 0 (both tiles) ----
        *(f16x8a*)&yA[eh * Y_ST + sub * 8]       = relu8(ps0a + pd0);
        *(f16x8a*)&yA[(8 + eh) * Y_ST + sub * 8] = relu8(ps0b + pd0);
        *(f16x8a*)&yB[eh * Y_ST + sub * 8]       = relu8(ps1a + pd1);
        *(f16x8a*)&yB[(8 + eh) * Y_ST + sub * 8] = relu8(ps1b + pd1);

        // ---- layer 1 (both) ----
        f16x8 a1A[2], a1B[2];
#pragma unroll
        for (int c = 0; c < 2; c++) {
            a1A[c] = *(const f16x8a*)&yA[lm * Y_ST + c * 32 + quad * 8];
            a1B[c] = *(const f16x8a*)&yB[lm * Y_ST + c * 32 + quad * 8];
        }
        f32x4 accA[4], accB[4];
#pragma unroll
        for (int q = 0; q < 4; q++) {
            accA[q] = (f32x4){bias1[q], bias1[q], bias1[q], bias1[q]};
            accB[q] = (f32x4){bias1[q], bias1[q], bias1[q], bias1[q]};
        }
#pragma unroll
        for (int c = 0; c < 2; c++)
#pragma unroll
            for (int q = 0; q < 4; q++) {
                accA[q] = __builtin_amdgcn_mfma_f32_16x16x32_f16(a1A[c], bw1[c][q], accA[q], 0, 0, 0);
                accB[q] = __builtin_amdgcn_mfma_f32_16x16x32_f16(a1B[c], bw1[c][q], accB[q], 0, 0, 0);
            }
#pragma unroll
        for (int q = 0; q < 4; q++)
#pragma unroll
            for (int r = 0; r < 4; r++) {
                yA[(quad * 4 + r) * Y_ST + q * 16 + lm] = (f16)fmaxf(accA[q][r], 0.f);
                yB[(quad * 4 + r) * Y_ST + q * 16 + lm] = (f16)fmaxf(accB[q][r], 0.f);
            }

        // ---- layer 2 (both) ----
        f16x8 a2A[2], a2B[2];
#pragma unroll
        for (int c = 0; c < 2; c++) {
            a2A[c] = *(const f16x8a*)&yA[lm * Y_ST + c * 32 + quad * 8];
            a2B[c] = *(const f16x8a*)&yB[lm * Y_ST + c * 32 + quad * 8];
        }
#pragma unroll
        for (int q = 0; q < 4; q++) {
            accA[q] = (f32x4){bias2[q], bias2[q], bias2[q], bias2[q]};
            accB[q] = (f32x4){bias2[q], bias2[q], bias2[q], bias2[q]};
        }
#pragma unroll
        for (int c = 0; c < 2; c++)
#pragma unroll
            for (int q = 0; q < 4; q++) {
                accA[q] = __builtin_amdgcn_mfma_f32_16x16x32_f16(a2A[c], bw2[c][q], accA[q], 0, 0, 0);
                accB[q] = __builtin_amdgcn_mfma_f32_16x16x32_f16(a2B[c], bw2[c][q], accB[q], 0, 0, 0);
            }

        // ---- accumulate + flush tile A ----
#pragma unroll
        for (int q = 0; q < 4; q++)
#pragma unroll
            for (int r = 0; r < 4; r++)
                if (quad * 4 + r < v0) accn[q] += accA[q][r];
        {
            const int curn = m0 & 0xFFFFF;
            const int nxt  = hasB ? (m1 & 0xFFFFF) : -1;
            if (nxt != curn) {
#pragma unroll
                for (int q = 0; q < 4; q++) {
                    float v = accn[q];
                    v += __shfl_xor(v, 16, 64);
                    v += __shfl_xor(v, 32, 64);
                    if (quad == 0) atomicAdd(&hout[(long)curn * 64 + q * 16 + lm], v);
                    accn[q] = 0.f;
                }
            }
        }
        // ---- accumulate + flush tile B ----
        if (hasB) {
#pragma unroll
            for (int q = 0; q < 4; q++)
#pragma unroll
                for (int r = 0; r < 4; r++)
                    if (quad * 4 + r < v1) accn[q] += accB[q][r];
            const int curn = m1 & 0xFFFFF;
            const int nxt  = (tt + 2 < t1) ? (m2 & 0xFFFFF) : -1;
            if (nxt != curn) {
#pragma unroll
                for (int q = 0; q < 4; q++) {
                    float v = accn[q];
                    v += __shfl_xor(v, 16, 64);
                    v += __shfl_xor(v, 32, 64);
                    if (quad == 0) atomicAdd(&hout[(long)curn * 64 + q * 16 + lm], v);
                    accn[q] = 0.f;
                }
            }
        }

        // ---- rotate pipeline ----
        m0 = m2; m1 = m3; m2 = m4; m3 = m5;
        s2a = s4a; s2b = s4b; s3a = s5a; s3b = s5b;
        ps0a = ps2a; ps0b = ps2b; pd0 = pd2;
        ps1a = ps3a; ps1b = ps3b; pd1 = pd3;
    }
}

__global__ __launch_bounds__(256) void k_lin_out(const int* __restrict__ flags,
                                                 const float* __restrict__ h,
                                                 const void* __restrict__ w,
                                                 const void* __restrict__ b,
                                                 float* __restrict__ out)
{
    int idx = blockIdx.x * 256 + threadIdx.x;
    if (idx >= N_NODES * D_OUT) return;
    const int isbf = flags[0];
    int n = idx >> 4, c = idx & 15;
    float acc = rdf(b, c, isbf);
    const float* hr = h + (long)n * D_HID;
#pragma unroll
    for (int i = 0; i < D_HID; i++) acc += hr[i] * rdf(w, (long)i * D_OUT + c, isbf);
    out[idx] = acc;
}

extern "C" void kernel_launch(void* const* d_in, const int* in_sizes, int n_in,
                              void* d_out, int out_size, void* d_ws, size_t ws_size,
                              hipStream_t stream)
{
    const void* x    = d_in[0];
    const int*  ei   = (const int*)d_in[2];
    const void* liw  = d_in[3];
    const void* lib  = d_in[4];
    const void* w0   = d_in[5];
    const void* b0   = d_in[6];
    const void* w1   = d_in[7];
    const void* b1   = d_in[8];
    const void* w2   = d_in[9];
    const void* b2   = d_in[10];
    const void* low  = d_in[11];
    const void* lob  = d_in[12];
    float* out = (float*)d_out;

    // ws (~37 MB, under proven 38.7 MB)
    char* wp = (char*)d_ws;
    int*   flags  = (int*)wp;                 wp += 256;
    float* hA     = (float*)wp;               wp += (size_t)N_NODES * D_HID * 4;
    f16*   Psrc   = (f16*)wp;                 wp += (size_t)N_NODES * D_HID * 2;
    f16*   Pdst   = (f16*)wp;                 wp += (size_t)N_NODES * D_HID * 2;
    f16*   wfrag  = (f16*)wp;                 wp += (size_t)4 * 32 * 64 * 8 * 2;  // 128 KB
    int*   hist   = (int*)wp;                 wp += (size_t)N_NODES * 4;
    int*   off    = (int*)wp;                 wp += ((size_t)N_NODES + 1) * 4;
    int*   cursor = (int*)wp;                 wp += (size_t)N_NODES * 4;
    int*   toff   = (int*)wp;                 wp += ((size_t)N_NODES + 1) * 4;
    int*   tcur   = (int*)wp;                 wp += (size_t)N_NODES * 4;
    int*   bsum   = (int*)wp;                 wp += 256 * 4;
    int*   boff   = (int*)wp;                 wp += 256 * 4;
    int*   ssrc   = (int*)wp;                 wp += (size_t)N_EDGES * 4;
    int*   tmeta  = (int*)wp;                 wp += (size_t)TMAX * 4;
    int*   spad   = (int*)wp;                 // TMAX*16 ints = 6.4 MB

    const int HN = N_NODES * D_HID;
    const int gH = (HN + 255) / 256;
    const int gE = (N_EDGES + 255) / 256;
    const int gN = (N_NODES + 255) / 256;

    k_detect<<<1, 64, 0, stream>>>((const unsigned short*)x, ei, flags);
    k_wprep<<<32, 256, 0, stream>>>(flags, w0, w1, w2, wfrag);

    // one-time: dst-sort + padded tile list (reused by all 4 graph blocks)
    k_zero_i<<<gN, 256, 0, stream>>>(hist, N_NODES);
    k_hist<<<gE, 256, 0, stream>>>(flags, ei, hist);
    k_scan1<<<NCHUNK, 256, 0, stream>>>(hist, bsum, 0);
    k_scan2<<<1, 256, 0, stream>>>(bsum, boff, off + N_NODES);
    k_scan3<<<NCHUNK, 256, 0, stream>>>(hist, boff, off, cursor, 0);
    k_scatter<<<gE, 256, 0, stream>>>(flags, ei, cursor, ssrc);
    k_scan1<<<NCHUNK, 256, 0, stream>>>(hist, bsum, 1);
    k_scan2<<<1, 256, 0, stream>>>(bsum, boff, toff + N_NODES);
    k_scan3<<<NCHUNK, 256, 0, stream>>>(hist, boff, toff, tcur, 1);
    k_tmeta<<<gN, 256, 0, stream>>>(hist, toff, tmeta);
    k_fill<<<(TMAX * 16) / 256, 256, 0, stream>>>(hist, off, toff, toff + N_NODES,
                                                  tmeta, ssrc, spad);

    k_lin_in<<<gH, 256, 0, stream>>>(flags, x, liw, lib, hA);

    for (int k = 0; k < 4; k++) {
        // k_proj reads hA, emits Psrc/Pdst, and zeroes hA for the aggregation
        k_proj<<<(N_NODES / 16 + 3) / 4, 256, 0, stream>>>(flags, hA, wfrag, b0,
                                                           Psrc, Pdst, k);
        k_edge_tile<<<1024, 256, 0, stream>>>(flags, spad, tmeta, toff,
                                              Psrc, Pdst, hA, wfrag, b1, b2, k);
    }

    k_lin_out<<<(N_NODES * D_OUT + 255) / 256, 256, 0, stream>>>(flags, hA, low, lob, out);
}

// Round 18
// 458.345 us; speedup vs baseline: 1.3923x; 1.0430x over previous
//
#include <hip/hip_runtime.h>
#include <hip/hip_bf16.h>

#define N_NODES 50000
#define N_EDGES 800000
#define D_IN    16
#define D_HID   64
#define D_OUT   16
#define NCHUNK  ((N_NODES + 255) / 256)   // 196 scan chunks
#define TMAX    100352                    // >= worst-case padded tile count

typedef __hip_bfloat16 bf16;
typedef _Float16 f16;
typedef _Float16 f16x8 __attribute__((ext_vector_type(8)));
typedef float    f32x4 __attribute__((ext_vector_type(4)));
typedef _Float16 f16x8a __attribute__((ext_vector_type(8), may_alias));

__device__ __forceinline__ float b2f(bf16 v) { return __bfloat162float(v); }
__device__ __forceinline__ int clampn(int v) {
    return v < 0 ? 0 : (v >= N_NODES ? N_NODES - 1 : v);
}
__device__ __forceinline__ float rdf(const void* p, long i, int isbf) {
    return isbf ? b2f(((const bf16*)p)[i]) : ((const float*)p)[i];
}
__device__ __forceinline__ f16x8 relu8(f16x8 v) {
#pragma unroll
    for (int j = 0; j < 8; j++) v[j] = v[j] > (f16)0 ? v[j] : (f16)0;
    return v;
}

// detect dtypes (block 0) + zero hist (all blocks) — fused, grid = NCHUNK
__global__ __launch_bounds__(256) void k_detect(const unsigned short* __restrict__ xw,
                                                const int* __restrict__ ei,
                                                int* __restrict__ flags,
                                                int* __restrict__ hist)
{
    int i = blockIdx.x * 256 + threadIdx.x;
    if (i < N_NODES) hist[i] = 0;
    if (blockIdx.x == 0 && threadIdx.x == 0) {
        int inband = 0;
        for (int j = 0; j < 256; j++) {
            unsigned short w = xw[2 * j];
            int e = (w >> 7) & 0xFF;
            if ((w & 0x7FFF) == 0 || (e >= 100 && e <= 140)) inband++;
        }
        flags[0] = (inband >= 192) ? 1 : 0;
        int z = 1;
        for (int j = 1; j < 128; j += 2) z &= (ei[j] == 0) ? 1 : 0;
        flags[1] = z;
    }
}

// ---------------------------------------------------------------------------
// One-time weight prep (R17-verified): pack MFMA B-fragments frag-major.
// ---------------------------------------------------------------------------
__global__ __launch_bounds__(256) void k_wprep(const int* __restrict__ flags,
                                               const void* __restrict__ gw0,
                                               const void* __restrict__ gw1,
                                               const void* __restrict__ gw2,
                                               f16* __restrict__ wfrag)
{
    int idx = blockIdx.x * 256 + threadIdx.x;      // [0, 8192)
    if (idx >= 4 * 32 * 64) return;
    const int isbf = flags[0];
    int kb = idx >> 11, rem = idx & 2047;
    int slot = rem >> 6, lane = rem & 63;
    int lm = lane & 15, quad = lane >> 4;
    f16* outp = wfrag + (long)idx * 8;
    if (slot < 16) {
        int c = slot >> 2, q = slot & 3;
        long base = (long)kb * 2 * D_HID * D_HID;
#pragma unroll
        for (int j = 0; j < 8; j++)
            outp[j] = (f16)rdf(gw0, base + (long)(c * 32 + quad * 8 + j) * 64 + q * 16 + lm, isbf);
    } else {
        const void* gw = (slot < 24) ? gw1 : gw2;
        int s = (slot < 24) ? slot - 16 : slot - 24;
        int c = s >> 2, q = s & 3;
        long base = (long)kb * D_HID * D_HID;
#pragma unroll
        for (int j = 0; j < 8; j++)
            outp[j] = (f16)rdf(gw, base + (long)(c * 32 + quad * 8 + j) * 64 + q * 16 + lm, isbf);
    }
}

// histogram, 4 edges/thread (4 independent atomics in flight per lane)
__global__ __launch_bounds__(256) void k_hist4(const int* __restrict__ flags,
                                               const int* __restrict__ eidx,
                                               int* __restrict__ hist)
{
    int base = (blockIdx.x * 256 + threadIdx.x) * 4;
    if (base >= N_EDGES) return;
    const int strd = flags[1] ? 2 : 1;
    const long dbase = flags[1] ? (long)(2 * N_EDGES) : (long)N_EDGES;
#pragma unroll
    for (int j = 0; j < 4; j++) {
        int e = base + j;
        if (e < N_EDGES)
            atomicAdd(&hist[clampn(eidx[dbase + (long)e * strd])], 1);
    }
}

// ---- dual exclusive scan (edge offsets AND tile offsets in one pipeline) ----
__global__ __launch_bounds__(256) void k_scan1(const int* __restrict__ hist,
                                               int* __restrict__ bsum_e,
                                               int* __restrict__ bsum_t)
{
    __shared__ int re[256], rt[256];
    const int t = threadIdx.x;
    int i = blockIdx.x * 256 + t;
    int v = (i < N_NODES) ? hist[i] : 0;
    re[t] = v; rt[t] = (v + 15) >> 4;
    __syncthreads();
    for (int d = 128; d > 0; d >>= 1) {
        if (t < d) { re[t] += re[t + d]; rt[t] += rt[t + d]; }
        __syncthreads();
    }
    if (t == 0) { bsum_e[blockIdx.x] = re[0]; bsum_t[blockIdx.x] = rt[0]; }
}

__global__ __launch_bounds__(256) void k_scan2(const int* __restrict__ bsum_e,
                                               const int* __restrict__ bsum_t,
                                               int* __restrict__ boff_e,
                                               int* __restrict__ boff_t,
                                               int* __restrict__ tot_e,
                                               int* __restrict__ tot_t)
{
    __shared__ int se[256], st_[256];
    const int t = threadIdx.x;
    se[t]  = (t < NCHUNK) ? bsum_e[t] : 0;
    st_[t] = (t < NCHUNK) ? bsum_t[t] : 0;
    __syncthreads();
    for (int d = 1; d < 256; d <<= 1) {
        int ve = (t >= d) ? se[t - d] : 0;
        int vt = (t >= d) ? st_[t - d] : 0;
        __syncthreads();
        se[t] += ve; st_[t] += vt;
        __syncthreads();
    }
    if (t < NCHUNK) {
        boff_e[t] = (t == 0) ? 0 : se[t - 1];
        boff_t[t] = (t == 0) ? 0 : st_[t - 1];
    }
    if (t == NCHUNK - 1) { tot_e[0] = se[t]; tot_t[0] = st_[t]; }
}

// final scan stage + inline tmeta emission (tmeta[t] = node | valid<<20)
__global__ __launch_bounds__(256) void k_scan3(const int* __restrict__ hist,
                                               const int* __restrict__ boff_e,
                                               const int* __restrict__ boff_t,
                                               int* __restrict__ off,
                                               int* __restrict__ cursor,
                                               int* __restrict__ toff,
                                               int* __restrict__ tmeta)
{
    __shared__ int se[256], st_[256];
    const int t = threadIdx.x;
    int i = blockIdx.x * 256 + t;
    int v = (i < N_NODES) ? hist[i] : 0;
    int w = (v + 15) >> 4;
    se[t] = v; st_[t] = w;
    __syncthreads();
    for (int d = 1; d < 256; d <<= 1) {
        int ue = (t >= d) ? se[t - d] : 0;
        int ut = (t >= d) ? st_[t - d] : 0;
        __syncthreads();
        se[t] += ue; st_[t] += ut;
        __syncthreads();
    }
    if (i < N_NODES) {
        int exE = boff_e[blockIdx.x] + se[t] - v;
        off[i] = exE; cursor[i] = exE;
        int exT = boff_t[blockIdx.x] + st_[t] - w;
        toff[i] = exT;
        for (int j = 0; j < w; j++)
            tmeta[exT + j] = i | (min(16, v - 16 * j) << 20);
    }
}

// scatter src-in-dst-order, 4 edges/thread: 4 independent atomic->write
// chains per lane (R17 post-mortem: 1 chain/thread = pure latency, VALU 0.4%)
__global__ __launch_bounds__(256) void k_scatter4(const int* __restrict__ flags,
                                                  const int* __restrict__ eidx,
                                                  int* __restrict__ cursor,
                                                  int* __restrict__ ssrc)
{
    int base = (blockIdx.x * 256 + threadIdx.x) * 4;
    if (base >= N_EDGES) return;
    const int strd = flags[1] ? 2 : 1;
    const long dbase = flags[1] ? (long)(2 * N_EDGES) : (long)N_EDGES;
    int d[4], s[4], pos[4], cnt = min(4, N_EDGES - base);
#pragma unroll
    for (int j = 0; j < 4; j++)
        if (j < cnt) {
            d[j] = clampn(eidx[dbase + (long)(base + j) * strd]);
            s[j] = clampn(eidx[(long)(base + j) * strd]);
        }
#pragma unroll
    for (int j = 0; j < 4; j++)
        if (j < cnt) pos[j] = atomicAdd(&cursor[d[j]], 1);
#pragma unroll
    for (int j = 0; j < 4; j++)
        if (j < cnt) ssrc[pos[j]] = s[j];
}

// padded src fill: one thread per tile slot (coalesced), last edge replicated
__global__ __launch_bounds__(256) void k_fill(const int* __restrict__ hist,
                                              const int* __restrict__ off,
                                              const int* __restrict__ toff,
                                              const int* __restrict__ totalp,
                                              const int* __restrict__ tmeta,
                                              const int* __restrict__ ssrc,
                                              int* __restrict__ spad)
{
    int idx = blockIdx.x * 256 + threadIdx.x;
    int t = idx >> 4, i = idx & 15;
    if (t >= totalp[0]) return;
    int n = tmeta[t] & 0xFFFFF;
    int j = t - toff[n];
    int dg = hist[n];
    spad[idx] = ssrc[off[n] + min(16 * j + i, dg - 1)];
}

__global__ __launch_bounds__(256) void k_lin_in(const int* __restrict__ flags,
                                                const void* __restrict__ x,
                                                const void* __restrict__ w,
                                                const void* __restrict__ b,
                                                float* __restrict__ h)
{
    int idx = blockIdx.x * 256 + threadIdx.x;
    if (idx >= N_NODES * D_HID) return;
    const int isbf = flags[0];
    int n = idx >> 6, c = idx & 63;
    float acc = rdf(b, c, isbf);
#pragma unroll
    for (int i = 0; i < D_IN; i++)
        acc += rdf(x, (long)n * D_IN + i, isbf) * rdf(w, (long)i * D_HID + c, isbf);
    h[idx] = acc;
}

// ---------------------------------------------------------------------------
// Node projection + hA zeroing (R17-verified): W0 frags from global wfrag.
// ---------------------------------------------------------------------------
#define HP_ST 72

__global__ __launch_bounds__(256) void k_proj(
    const int* __restrict__ flags, float* hio,
    const f16* __restrict__ wfrag, const void* __restrict__ gb0,
    f16* __restrict__ psrc, f16* __restrict__ pdst, int kblk)
{
    __shared__ f16 hL_s[4][16 * HP_ST];     // 9216 B

    const int tid  = threadIdx.x;
    const int isbf = flags[0];
    const int wv = tid >> 6, ln = tid & 63;
    const int lm = ln & 15, quad = ln >> 4;
    f16* hL = hL_s[wv];

    const int g = blockIdx.x * 4 + wv;
    if (g >= N_NODES / 16) return;
    const int n0 = g * 16;

    const f16* wb = wfrag + (long)kblk * 32 * 64 * 8;

#pragma unroll
    for (int i = 0; i < 16; i++) {
        int idx = i * 64 + ln;
        hL[(idx >> 6) * HP_ST + (idx & 63)] = (f16)hio[(long)n0 * 64 + idx];
    }
#pragma unroll
    for (int i = 0; i < 16; i++)
        hio[(long)n0 * 64 + i * 64 + ln] = 0.f;

    f16x8 a[2];
#pragma unroll
    for (int c = 0; c < 2; c++)
        a[c] = *(const f16x8a*)&hL[lm * HP_ST + c * 32 + quad * 8];

    f32x4 accS[4], accD[4];
#pragma unroll
    for (int q = 0; q < 4; q++) {
        float bd = rdf(gb0, (long)kblk * 64 + q * 16 + lm, isbf);
        accS[q] = (f32x4){0.f, 0.f, 0.f, 0.f};
        accD[q] = (f32x4){bd, bd, bd, bd};
    }
#pragma unroll
    for (int c = 0; c < 2; c++)
#pragma unroll
        for (int q = 0; q < 4; q++) {
            f16x8 bs = *(const f16x8a*)&wb[(((c + 0) * 4 + q) * 64 + ln) * 8];
            f16x8 bd = *(const f16x8a*)&wb[(((c + 2) * 4 + q) * 64 + ln) * 8];
            accS[q] = __builtin_amdgcn_mfma_f32_16x16x32_f16(a[c], bs, accS[q], 0, 0, 0);
            accD[q] = __builtin_amdgcn_mfma_f32_16x16x32_f16(a[c], bd, accD[q], 0, 0, 0);
        }
#pragma unroll
    for (int q = 0; q < 4; q++)
#pragma unroll
        for (int r = 0; r < 4; r++) {
            long o = (long)(n0 + quad * 4 + r) * 64 + q * 16 + lm;
            psrc[o] = (f16)accS[q][r];
            pdst[o] = (f16)accD[q][r];
        }
}

// ---------------------------------------------------------------------------
// Uniform tile-list aggregation, pair-ILP, global wfrag (R16/R17-verified).
// ---------------------------------------------------------------------------
#define Y_ST 72

__global__ __launch_bounds__(256) void k_edge_tile(
    const int* __restrict__ flags,
    const int* __restrict__ ssrc_pad, const int* __restrict__ tmeta,
    const int* __restrict__ toff,
    const f16* __restrict__ psrc, const f16* __restrict__ pdst,
    float* __restrict__ hout,
    const f16* __restrict__ wfrag, const void* __restrict__ gb1,
    const void* __restrict__ gb2, int kblk)
{
    __shared__ f16 y_s[4][2][16 * Y_ST];     // 18432 B total

    const int tid  = threadIdx.x;
    const int isbf = flags[0];
    const int wv = tid >> 6, ln = tid & 63;
    const int lm = ln & 15, quad = ln >> 4;

    const f16* wb = wfrag + (long)kblk * 32 * 64 * 8;
    f16x8 bw1[2][4], bw2[2][4];
#pragma unroll
    for (int c = 0; c < 2; c++)
#pragma unroll
        for (int q = 0; q < 4; q++) {
            bw1[c][q] = *(const f16x8a*)&wb[((16 + c * 4 + q) * 64 + ln) * 8];
            bw2[c][q] = *(const f16x8a*)&wb[((24 + c * 4 + q) * 64 + ln) * 8];
        }
    float bias1[4], bias2[4];
#pragma unroll
    for (int q = 0; q < 4; q++) {
        bias1[q] = rdf(gb1, (long)kblk * 64 + q * 16 + lm, isbf);
        bias2[q] = rdf(gb2, (long)kblk * 64 + q * 16 + lm, isbf);
    }

    f16* yA = y_s[wv][0];
    f16* yB = y_s[wv][1];
    const int sub = ln & 7, eh = ln >> 3;

    const int T  = toff[N_NODES];
    const int W  = gridDim.x * 4;
    const int gw = blockIdx.x * 4 + wv;
    const int t0 = (int)((long)gw * T / W);
    const int t1 = (int)((long)(gw + 1) * T / W);
    if (t0 >= t1) return;

    // ---- pipeline prologue: meta tt..tt+3, data tt..tt+1, idx tt+2..tt+3
    int tcA = t0, tcB = min(t0 + 1, T - 1);
    int tc2 = min(t0 + 2, T - 1), tc3 = min(t0 + 3, T - 1);
    int m0 = tmeta[tcA], m1 = tmeta[tcB], m2 = tmeta[tc2], m3 = tmeta[tc3];
    int s2a = ssrc_pad[tc2 * 16 + eh], s2b = ssrc_pad[tc2 * 16 + 8 + eh];
    int s3a = ssrc_pad[tc3 * 16 + eh], s3b = ssrc_pad[tc3 * 16 + 8 + eh];
    int s0a = ssrc_pad[tcA * 16 + eh], s0b = ssrc_pad[tcA * 16 + 8 + eh];
    int s1a = ssrc_pad[tcB * 16 + eh], s1b = ssrc_pad[tcB * 16 + 8 + eh];
    f16x8 ps0a = *(const f16x8a*)&psrc[(long)s0a * 64 + sub * 8];
    f16x8 ps0b = *(const f16x8a*)&psrc[(long)s0b * 64 + sub * 8];
    f16x8 pd0  = *(const f16x8a*)&pdst[(long)(m0 & 0xFFFFF) * 64 + sub * 8];
    f16x8 ps1a = *(const f16x8a*)&psrc[(long)s1a * 64 + sub * 8];
    f16x8 ps1b = *(const f16x8a*)&psrc[(long)s1b * 64 + sub * 8];
    f16x8 pd1  = *(const f16x8a*)&pdst[(long)(m1 & 0xFFFFF) * 64 + sub * 8];

    float accn[4] = {0.f, 0.f, 0.f, 0.f};

    for (int tt = t0; tt < t1; tt += 2) {
        // ---- prefetch meta/indices for tiles tt+4, tt+5 ----
        const int tc4 = min(tt + 4, T - 1), tc5 = min(tt + 5, T - 1);
        int m4 = tmeta[tc4], m5 = tmeta[tc5];
        int s4a = ssrc_pad[tc4 * 16 + eh], s4b = ssrc_pad[tc4 * 16 + 8 + eh];
        int s5a = ssrc_pad[tc5 * 16 + eh], s5b = ssrc_pad[tc5 * 16 + 8 + eh];
        // ---- load gather data for tiles tt+2, tt+3 ----
        f16x8 ps2a = *(const f16x8a*)&psrc[(long)s2a * 64 + sub * 8];
        f16x8 ps2b = *(const f16x8a*)&psrc[(long)s2b * 64 + sub * 8];
        f16x8 pd2  = *(const f16x8a*)&pdst[(long)(m2 & 0xFFFFF) * 64 + sub * 8];
        f16x8 ps3a = *(const f16x8a*)&psrc[(long)s3a * 64 + sub * 8];
        f16x8 ps3b = *(const f16x8a*)&psrc[(long)s3b * 64 + sub * 8];
        f16x8 pd3  = *(const f16x8a*)&pdst[(long)(m3 & 0xFFFFF) * 64 + sub * 8];

        const int hasB = (tt + 1 < t1);
        const int v0 = m0 >> 20;
        const int v1 = hasB ? (m1 >> 20) : 0;

        // ---- layer 0 (both tiles) ----
        *(f16x8a*)&yA[eh * Y_ST + sub * 8]       = relu8(ps0a + pd0);
        *(f16x8a*)&yA[(8 + eh) * Y_ST + sub * 8] = relu8(ps0b + pd0);
        *(f16x8a*)&yB[eh * Y_ST + sub * 8]       = relu8(ps1a + pd1);
        *(f16x8a*)&yB[(8 + eh) * Y_ST + sub * 8] = relu8(ps1b + pd1);

        // ---- layer 1 (both) ----
        f16x8 a1A[2], a1B[2];
#pragma unroll
        for (int c = 0; c < 2; c++) {
            a1A[c] = *(const f16x8a*)&yA[lm * Y_ST + c * 32 + quad * 8];
            a1B[c] = *(const f16x8a*)&yB[lm * Y_ST + c * 32 + quad * 8];
        }
        f32x4 accA[4], accB[4];
#pragma unroll
        for (int q = 0; q < 4; q++) {
            accA[q] = (f32x4){bias1[q], bias1[q], bias1[q], bias1[q]};
            accB[q] = (f32x4){bias1[q], bias1[q], bias1[q], bias1[q]};
        }
#pragma unroll
        for (int c = 0; c < 2; c++)
#pragma unroll
            for (int q = 0; q < 4; q++) {
                accA[q] = __builtin_amdgcn_mfma_f32_16x16x32_f16(a1A[c], bw1[c][q], accA[q], 0, 0, 0);
                accB[q] = __builtin_amdgcn_mfma_f32_16x16x32_f16(a1B[c], bw1[c][q], accB[q], 0, 0, 0);
            }
#pragma unroll
        for (int q = 0; q < 4; q++)
#pragma unroll
            for (int r = 0; r < 4; r++) {
                yA[(quad * 4 + r) * Y_ST + q * 16 + lm] = (f16)fmaxf(accA[q][r], 0.f);
                yB[(quad * 4 + r) * Y_ST + q * 16 + lm] = (f16)fmaxf(accB[q][r], 0.f);
            }

        // ---- layer 2 (both) ----
        f16x8 a2A[2], a2B[2];
#pragma unroll
        for (int c = 0; c < 2; c++) {
            a2A[c] = *(const f16x8a*)&yA[lm * Y_ST + c * 32 + quad * 8];
            a2B[c] = *(const f16x8a*)&yB[lm * Y_ST + c * 32 + quad * 8];
        }
#pragma unroll
        for (int q = 0; q < 4; q++) {
            accA[q] = (f32x4){bias2[q], bias2[q], bias2[q], bias2[q]};
            accB[q] = (f32x4){bias2[q], bias2[q], bias2[q], bias2[q]};
        }
#pragma unroll
        for (int c = 0; c < 2; c++)
#pragma unroll
            for (int q = 0; q < 4; q++) {
                accA[q] = __builtin_amdgcn_mfma_f32_16x16x32_f16(a2A[c], bw2[c][q], accA[q], 0, 0, 0);
                accB[q] = __builtin_amdgcn_mfma_f32_16x16x32_f16(a2B[c], bw2[c][q], accB[q], 0, 0, 0);
            }

        // ---- accumulate + flush tile A ----
#pragma unroll
        for (int q = 0; q < 4; q++)
#pragma unroll
            for (int r = 0; r < 4; r++)
                if (quad * 4 + r < v0) accn[q] += accA[q][r];
        {
            const int curn = m0 & 0xFFFFF;
            const int nxt  = hasB ? (m1 & 0xFFFFF) : -1;
            if (nxt != curn) {
#pragma unroll
                for (int q = 0; q < 4; q++) {
                    float v = accn[q];
                    v += __shfl_xor(v, 16, 64);
                    v += __shfl_xor(v, 32, 64);
                    if (quad == 0) atomicAdd(&hout[(long)curn * 64 + q * 16 + lm], v);
                    accn[q] = 0.f;
                }
            }
        }
        // ---- accumulate + flush tile B ----
        if (hasB) {
#pragma unroll
            for (int q = 0; q < 4; q++)
#pragma unroll
                for (int r = 0; r < 4; r++)
                    if (quad * 4 + r < v1) accn[q] += accB[q][r];
            const int curn = m1 & 0xFFFFF;
            const int nxt  = (tt + 2 < t1) ? (m2 & 0xFFFFF) : -1;
            if (nxt != curn) {
#pragma unroll
                for (int q = 0; q < 4; q++) {
                    float v = accn[q];
                    v += __shfl_xor(v, 16, 64);
                    v += __shfl_xor(v, 32, 64);
                    if (quad == 0) atomicAdd(&hout[(long)curn * 64 + q * 16 + lm], v);
                    accn[q] = 0.f;
                }
            }
        }

        // ---- rotate pipeline ----
        m0 = m2; m1 = m3; m2 = m4; m3 = m5;
        s2a = s4a; s2b = s4b; s3a = s5a; s3b = s5b;
        ps0a = ps2a; ps0b = ps2b; pd0 = pd2;
        ps1a = ps3a; ps1b = ps3b; pd1 = pd3;
    }
}

__global__ __launch_bounds__(256) void k_lin_out(const int* __restrict__ flags,
                                                 const float* __restrict__ h,
                                                 const void* __restrict__ w,
                                                 const void* __restrict__ b,
                                                 float* __restrict__ out)
{
    int idx = blockIdx.x * 256 + threadIdx.x;
    if (idx >= N_NODES * D_OUT) return;
    const int isbf = flags[0];
    int n = idx >> 4, c = idx & 15;
    float acc = rdf(b, c, isbf);
    const float* hr = h + (long)n * D_HID;
#pragma unroll
    for (int i = 0; i < D_HID; i++) acc += hr[i] * rdf(w, (long)i * D_OUT + c, isbf);
    out[idx] = acc;
}

extern "C" void kernel_launch(void* const* d_in, const int* in_sizes, int n_in,
                              void* d_out, int out_size, void* d_ws, size_t ws_size,
                              hipStream_t stream)
{
    const void* x    = d_in[0];
    const int*  ei   = (const int*)d_in[2];
    const void* liw  = d_in[3];
    const void* lib  = d_in[4];
    const void* w0   = d_in[5];
    const void* b0   = d_in[6];
    const void* w1   = d_in[7];
    const void* b1   = d_in[8];
    const void* w2   = d_in[9];
    const void* b2   = d_in[10];
    const void* low  = d_in[11];
    const void* lob  = d_in[12];
    float* out = (float*)d_out;

    // ws (~37 MB, under proven 38.7 MB)
    char* wp = (char*)d_ws;
    int*   flags  = (int*)wp;                 wp += 256;
    float* hA     = (float*)wp;               wp += (size_t)N_NODES * D_HID * 4;
    f16*   Psrc   = (f16*)wp;                 wp += (size_t)N_NODES * D_HID * 2;
    f16*   Pdst   = (f16*)wp;                 wp += (size_t)N_NODES * D_HID * 2;
    f16*   wfrag  = (f16*)wp;                 wp += (size_t)4 * 32 * 64 * 8 * 2;  // 128 KB
    int*   hist   = (int*)wp;                 wp += (size_t)N_NODES * 4;
    int*   off    = (int*)wp;                 wp += ((size_t)N_NODES + 1) * 4;
    int*   cursor = (int*)wp;                 wp += (size_t)N_NODES * 4;
    int*   toff   = (int*)wp;                 wp += ((size_t)N_NODES + 1) * 4;
    int*   bsum_e = (int*)wp;                 wp += 256 * 4;
    int*   bsum_t = (int*)wp;                 wp += 256 * 4;
    int*   boff_e = (int*)wp;                 wp += 256 * 4;
    int*   boff_t = (int*)wp;                 wp += 256 * 4;
    int*   ssrc   = (int*)wp;                 wp += (size_t)N_EDGES * 4;
    int*   tmeta  = (int*)wp;                 wp += (size_t)TMAX * 4;
    int*   spad   = (int*)wp;                 // TMAX*16 ints = 6.4 MB

    const int HN = N_NODES * D_HID;
    const int gH = (HN + 255) / 256;
    const int gE4 = (N_EDGES / 4 + 255) / 256;

    // detect + hist zeroing fused
    k_detect<<<NCHUNK, 256, 0, stream>>>((const unsigned short*)x, ei, flags, hist);
    k_wprep<<<32, 256, 0, stream>>>(flags, w0, w1, w2, wfrag);

    // one-time: dst-sort + padded tile list (reused by all 4 graph blocks)
    k_hist4<<<gE4, 256, 0, stream>>>(flags, ei, hist);
    k_scan1<<<NCHUNK, 256, 0, stream>>>(hist, bsum_e, bsum_t);
    k_scan2<<<1, 256, 0, stream>>>(bsum_e, bsum_t, boff_e, boff_t,
                                   off + N_NODES, toff + N_NODES);
    k_scan3<<<NCHUNK, 256, 0, stream>>>(hist, boff_e, boff_t, off, cursor, toff, tmeta);
    k_scatter4<<<gE4, 256, 0, stream>>>(flags, ei, cursor, ssrc);
    k_fill<<<(TMAX * 16) / 256, 256, 0, stream>>>(hist, off, toff, toff + N_NODES,
                                                  tmeta, ssrc, spad);

    k_lin_in<<<gH, 256, 0, stream>>>(flags, x, liw, lib, hA);

    for (int k = 0; k < 4; k++) {
        // k_proj reads hA, emits Psrc/Pdst, and zeroes hA for the aggregation
        k_proj<<<(N_NODES / 16 + 3) / 4, 256, 0, stream>>>(flags, hA, wfrag, b0,
                                                           Psrc, Pdst, k);
        k_edge_tile<<<1024, 256, 0, stream>>>(flags, spad, tmeta, toff,
                                              Psrc, Pdst, hA, wfrag, b1, b2, k);
    }

    k_lin_out<<<(N_NODES * D_OUT + 255) / 256, 256, 0, stream>>>(flags, hA, low, lob, out);
}

// Round 19
// 455.607 us; speedup vs baseline: 1.4007x; 1.0060x over previous
//
#include <hip/hip_runtime.h>
#include <hip/hip_bf16.h>

#define N_NODES 50000
#define N_EDGES 800000
#define D_IN    16
#define D_HID   64
#define D_OUT   16
#define NCHUNK  ((N_NODES + 255) / 256)   // 196 scan chunks
#define TMAX    100352                    // >= worst-case padded tile count
#define GE4     ((N_EDGES / 4 + 255) / 256)      // 782 blocks (4 edges/thread)
#define GH      ((N_NODES * D_HID + 255) / 256)  // 12500 blocks

typedef __hip_bfloat16 bf16;
typedef _Float16 f16;
typedef _Float16 f16x8 __attribute__((ext_vector_type(8)));
typedef float    f32x4 __attribute__((ext_vector_type(4)));
typedef _Float16 f16x8a __attribute__((ext_vector_type(8), may_alias));

__device__ __forceinline__ float b2f(bf16 v) { return __bfloat162float(v); }
__device__ __forceinline__ int clampn(int v) {
    return v < 0 ? 0 : (v >= N_NODES ? N_NODES - 1 : v);
}
__device__ __forceinline__ float rdf(const void* p, long i, int isbf) {
    return isbf ? b2f(((const bf16*)p)[i]) : ((const float*)p)[i];
}
__device__ __forceinline__ f16x8 relu8(f16x8 v) {
#pragma unroll
    for (int j = 0; j < 8; j++) v[j] = v[j] > (f16)0 ? v[j] : (f16)0;
    return v;
}

// detect dtypes (block 0) + zero hist (all blocks) — fused, grid = NCHUNK
__global__ __launch_bounds__(256) void k_detect(const unsigned short* __restrict__ xw,
                                                const int* __restrict__ ei,
                                                int* __restrict__ flags,
                                                int* __restrict__ hist)
{
    int i = blockIdx.x * 256 + threadIdx.x;
    if (i < N_NODES) hist[i] = 0;
    if (blockIdx.x == 0 && threadIdx.x == 0) {
        int inband = 0;
        for (int j = 0; j < 256; j++) {
            unsigned short w = xw[2 * j];
            int e = (w >> 7) & 0xFF;
            if ((w & 0x7FFF) == 0 || (e >= 100 && e <= 140)) inband++;
        }
        flags[0] = (inband >= 192) ? 1 : 0;
        int z = 1;
        for (int j = 1; j < 128; j += 2) z &= (ei[j] == 0) ? 1 : 0;
        flags[1] = z;
    }
}

// ---------------------------------------------------------------------------
// ROUND-19 fused prep (all three depend only on flags; block-partitioned):
//   blocks [0,32)           : weight-fragment packing (R17-verified)
//   blocks [32, 32+GE4)     : dst histogram, 4 edges/thread
//   blocks [32+GE4, +GH)    : lin_in  h = x@Win + bin
// ---------------------------------------------------------------------------
__global__ __launch_bounds__(256) void k_prep(const int* __restrict__ flags,
                                              const void* __restrict__ gw0,
                                              const void* __restrict__ gw1,
                                              const void* __restrict__ gw2,
                                              f16* __restrict__ wfrag,
                                              const int* __restrict__ eidx,
                                              int* __restrict__ hist,
                                              const void* __restrict__ x,
                                              const void* __restrict__ liw,
                                              const void* __restrict__ lib,
                                              float* __restrict__ h)
{
    const int isbf = flags[0];
    const int bid = blockIdx.x;
    if (bid < 32) {
        // ---- weight prep ----
        int idx = bid * 256 + threadIdx.x;      // [0, 8192)
        int kb = idx >> 11, rem = idx & 2047;
        int slot = rem >> 6, lane = rem & 63;
        int lm = lane & 15, quad = lane >> 4;
        f16* outp = wfrag + (long)idx * 8;
        if (slot < 16) {
            int c = slot >> 2, q = slot & 3;
            long base = (long)kb * 2 * D_HID * D_HID;
#pragma unroll
            for (int j = 0; j < 8; j++)
                outp[j] = (f16)rdf(gw0, base + (long)(c * 32 + quad * 8 + j) * 64 + q * 16 + lm, isbf);
        } else {
            const void* gw = (slot < 24) ? gw1 : gw2;
            int s = (slot < 24) ? slot - 16 : slot - 24;
            int c = s >> 2, q = s & 3;
            long base = (long)kb * D_HID * D_HID;
#pragma unroll
            for (int j = 0; j < 8; j++)
                outp[j] = (f16)rdf(gw, base + (long)(c * 32 + quad * 8 + j) * 64 + q * 16 + lm, isbf);
        }
    } else if (bid < 32 + GE4) {
        // ---- histogram (4 independent atomics in flight per lane) ----
        int base = ((bid - 32) * 256 + threadIdx.x) * 4;
        if (base >= N_EDGES) return;
        const int strd = flags[1] ? 2 : 1;
        const long dbase = flags[1] ? (long)(2 * N_EDGES) : (long)N_EDGES;
#pragma unroll
        for (int j = 0; j < 4; j++) {
            int e = base + j;
            if (e < N_EDGES)
                atomicAdd(&hist[clampn(eidx[dbase + (long)e * strd])], 1);
        }
    } else {
        // ---- lin_in ----
        int idx = (bid - 32 - GE4) * 256 + threadIdx.x;
        if (idx >= N_NODES * D_HID) return;
        int n = idx >> 6, c = idx & 63;
        float acc = rdf(lib, c, isbf);
#pragma unroll
        for (int i = 0; i < D_IN; i++)
            acc += rdf(x, (long)n * D_IN + i, isbf) * rdf(liw, (long)i * D_HID + c, isbf);
        h[idx] = acc;
    }
}

// ---- dual exclusive scan (edge offsets AND tile offsets in one pipeline) ----
__global__ __launch_bounds__(256) void k_scan1(const int* __restrict__ hist,
                                               int* __restrict__ bsum_e,
                                               int* __restrict__ bsum_t)
{
    __shared__ int re[256], rt[256];
    const int t = threadIdx.x;
    int i = blockIdx.x * 256 + t;
    int v = (i < N_NODES) ? hist[i] : 0;
    re[t] = v; rt[t] = (v + 15) >> 4;
    __syncthreads();
    for (int d = 128; d > 0; d >>= 1) {
        if (t < d) { re[t] += re[t + d]; rt[t] += rt[t + d]; }
        __syncthreads();
    }
    if (t == 0) { bsum_e[blockIdx.x] = re[0]; bsum_t[blockIdx.x] = rt[0]; }
}

__global__ __launch_bounds__(256) void k_scan2(const int* __restrict__ bsum_e,
                                               const int* __restrict__ bsum_t,
                                               int* __restrict__ boff_e,
                                               int* __restrict__ boff_t,
                                               int* __restrict__ tot_e,
                                               int* __restrict__ tot_t)
{
    __shared__ int se[256], st_[256];
    const int t = threadIdx.x;
    se[t]  = (t < NCHUNK) ? bsum_e[t] : 0;
    st_[t] = (t < NCHUNK) ? bsum_t[t] : 0;
    __syncthreads();
    for (int d = 1; d < 256; d <<= 1) {
        int ve = (t >= d) ? se[t - d] : 0;
        int vt = (t >= d) ? st_[t - d] : 0;
        __syncthreads();
        se[t] += ve; st_[t] += vt;
        __syncthreads();
    }
    if (t < NCHUNK) {
        boff_e[t] = (t == 0) ? 0 : se[t - 1];
        boff_t[t] = (t == 0) ? 0 : st_[t - 1];
    }
    if (t == NCHUNK - 1) { tot_e[0] = se[t]; tot_t[0] = st_[t]; }
}

// final scan stage + inline tmeta emission (tmeta[t] = node | valid<<20)
__global__ __launch_bounds__(256) void k_scan3(const int* __restrict__ hist,
                                               const int* __restrict__ boff_e,
                                               const int* __restrict__ boff_t,
                                               int* __restrict__ off,
                                               int* __restrict__ cursor,
                                               int* __restrict__ toff,
                                               int* __restrict__ tmeta)
{
    __shared__ int se[256], st_[256];
    const int t = threadIdx.x;
    int i = blockIdx.x * 256 + t;
    int v = (i < N_NODES) ? hist[i] : 0;
    int w = (v + 15) >> 4;
    se[t] = v; st_[t] = w;
    __syncthreads();
    for (int d = 1; d < 256; d <<= 1) {
        int ue = (t >= d) ? se[t - d] : 0;
        int ut = (t >= d) ? st_[t - d] : 0;
        __syncthreads();
        se[t] += ue; st_[t] += ut;
        __syncthreads();
    }
    if (i < N_NODES) {
        int exE = boff_e[blockIdx.x] + se[t] - v;
        off[i] = exE; cursor[i] = exE;
        int exT = boff_t[blockIdx.x] + st_[t] - w;
        toff[i] = exT;
        for (int j = 0; j < w; j++)
            tmeta[exT + j] = i | (min(16, v - 16 * j) << 20);
    }
}

// scatter src-in-dst-order, 4 edges/thread (R18-verified)
__global__ __launch_bounds__(256) void k_scatter4(const int* __restrict__ flags,
                                                  const int* __restrict__ eidx,
                                                  int* __restrict__ cursor,
                                                  int* __restrict__ ssrc)
{
    int base = (blockIdx.x * 256 + threadIdx.x) * 4;
    if (base >= N_EDGES) return;
    const int strd = flags[1] ? 2 : 1;
    const long dbase = flags[1] ? (long)(2 * N_EDGES) : (long)N_EDGES;
    int d[4], s[4], pos[4], cnt = min(4, N_EDGES - base);
#pragma unroll
    for (int j = 0; j < 4; j++)
        if (j < cnt) {
            d[j] = clampn(eidx[dbase + (long)(base + j) * strd]);
            s[j] = clampn(eidx[(long)(base + j) * strd]);
        }
#pragma unroll
    for (int j = 0; j < 4; j++)
        if (j < cnt) pos[j] = atomicAdd(&cursor[d[j]], 1);
#pragma unroll
    for (int j = 0; j < 4; j++)
        if (j < cnt) ssrc[pos[j]] = s[j];
}

// padded src fill: one thread per tile slot (coalesced), last edge replicated
__global__ __launch_bounds__(256) void k_fill(const int* __restrict__ hist,
                                              const int* __restrict__ off,
                                              const int* __restrict__ toff,
                                              const int* __restrict__ totalp,
                                              const int* __restrict__ tmeta,
                                              const int* __restrict__ ssrc,
                                              int* __restrict__ spad)
{
    int idx = blockIdx.x * 256 + threadIdx.x;
    int t = idx >> 4, i = idx & 15;
    if (t >= totalp[0]) return;
    int n = tmeta[t] & 0xFFFFF;
    int j = t - toff[n];
    int dg = hist[n];
    spad[idx] = ssrc[off[n] + min(16 * j + i, dg - 1)];
}

// ---------------------------------------------------------------------------
// Node projection (R17-verified). ROUND-19: bulk h-zeroing REMOVED (edge
// kernel now plain-stores every deg>0 node); rare zero-in-degree nodes get
// their h rows zeroed here (hist[n]==0 — expected ~0 nodes, but required).
// ---------------------------------------------------------------------------
#define HP_ST 72

__global__ __launch_bounds__(256) void k_proj(
    const int* __restrict__ flags, float* hio,
    const f16* __restrict__ wfrag, const void* __restrict__ gb0,
    const int* __restrict__ hist,
    f16* __restrict__ psrc, f16* __restrict__ pdst, int kblk)
{
    __shared__ f16 hL_s[4][16 * HP_ST];     // 9216 B

    const int tid  = threadIdx.x;
    const int isbf = flags[0];
    const int wv = tid >> 6, ln = tid & 63;
    const int lm = ln & 15, quad = ln >> 4;
    f16* hL = hL_s[wv];

    const int g = blockIdx.x * 4 + wv;
    if (g >= N_NODES / 16) return;
    const int n0 = g * 16;

    const f16* wb = wfrag + (long)kblk * 32 * 64 * 8;

#pragma unroll
    for (int i = 0; i < 16; i++) {
        int idx = i * 64 + ln;
        hL[(idx >> 6) * HP_ST + (idx & 63)] = (f16)hio[(long)n0 * 64 + idx];
    }
    // rare: zero-in-degree nodes are never stored by the aggregation — zero
    // their rows so next proj / lin_out read segment_sum = 0 (read above came
    // first in program order, so psrc for this node is still correct)
#pragma unroll
    for (int i = 0; i < 16; i++)
        if (hist[n0 + i] == 0) hio[(long)(n0 + i) * 64 + ln] = 0.f;

    f16x8 a[2];
#pragma unroll
    for (int c = 0; c < 2; c++)
        a[c] = *(const f16x8a*)&hL[lm * HP_ST + c * 32 + quad * 8];

    f32x4 accS[4], accD[4];
#pragma unroll
    for (int q = 0; q < 4; q++) {
        float bd = rdf(gb0, (long)kblk * 64 + q * 16 + lm, isbf);
        accS[q] = (f32x4){0.f, 0.f, 0.f, 0.f};
        accD[q] = (f32x4){bd, bd, bd, bd};
    }
#pragma unroll
    for (int c = 0; c < 2; c++)
#pragma unroll
        for (int q = 0; q < 4; q++) {
            f16x8 bs = *(const f16x8a*)&wb[(((c + 0) * 4 + q) * 64 + ln) * 8];
            f16x8 bd = *(const f16x8a*)&wb[(((c + 2) * 4 + q) * 64 + ln) * 8];
            accS[q] = __builtin_amdgcn_mfma_f32_16x16x32_f16(a[c], bs, accS[q], 0, 0, 0);
            accD[q] = __builtin_amdgcn_mfma_f32_16x16x32_f16(a[c], bd, accD[q], 0, 0, 0);
        }
#pragma unroll
    for (int q = 0; q < 4; q++)
#pragma unroll
        for (int r = 0; r < 4; r++) {
            long o = (long)(n0 + quad * 4 + r) * 64 + q * 16 + lm;
            psrc[o] = (f16)accS[q][r];
            pdst[o] = (f16)accD[q][r];
        }
}

// ---------------------------------------------------------------------------
// Uniform tile-list aggregation, pair-ILP, global wfrag (R16-18 verified).
// ROUND-19: NODE-ALIGNED wave ownership — ranges snap to node boundaries
// (identical adjustment loop at both ends keeps the partition exact), so
// each node is flushed by exactly one wave with a PLAIN STORE (no atomics,
// no pre-zeroed h).
// ---------------------------------------------------------------------------
#define Y_ST 72

__global__ __launch_bounds__(256) void k_edge_tile(
    const int* __restrict__ flags,
    const int* __restrict__ ssrc_pad, const int* __restrict__ tmeta,
    const int* __restrict__ toff,
    const f16* __restrict__ psrc, const f16* __restrict__ pdst,
    float* __restrict__ hout,
    const f16* __restrict__ wfrag, const void* __restrict__ gb1,
    const void* __restrict__ gb2, int kblk)
{
    __shared__ f16 y_s[4][2][16 * Y_ST];     // 18432 B total

    const int tid  = threadIdx.x;
    const int isbf = flags[0];
    const int wv = tid >> 6, ln = tid & 63;
    const int lm = ln & 15, quad = ln >> 4;

    const f16* wb = wfrag + (long)kblk * 32 * 64 * 8;
    f16x8 bw1[2][4], bw2[2][4];
#pragma unroll
    for (int c = 0; c < 2; c++)
#pragma unroll
        for (int q = 0; q < 4; q++) {
            bw1[c][q] = *(const f16x8a*)&wb[((16 + c * 4 + q) * 64 + ln) * 8];
            bw2[c][q] = *(const f16x8a*)&wb[((24 + c * 4 + q) * 64 + ln) * 8];
        }
    float bias1[4], bias2[4];
#pragma unroll
    for (int q = 0; q < 4; q++) {
        bias1[q] = rdf(gb1, (long)kblk * 64 + q * 16 + lm, isbf);
        bias2[q] = rdf(gb2, (long)kblk * 64 + q * 16 + lm, isbf);
    }

    f16* yA = y_s[wv][0];
    f16* yB = y_s[wv][1];
    const int sub = ln & 7, eh = ln >> 3;

    const int T  = toff[N_NODES];
    const int W  = gridDim.x * 4;
    const int gw = blockIdx.x * 4 + wv;
    int t0 = (int)((long)gw * T / W);
    int t1 = (int)((long)(gw + 1) * T / W);
    // node-aligned ownership: skip continuation tiles at start, extend range
    // past the end while the last node continues (same loop both sides ->
    // waves' ranges stay an exact partition of [0, T))
    if (t0 > 0)
        while (t0 < T && (tmeta[t0] & 0xFFFFF) == (tmeta[t0 - 1] & 0xFFFFF)) t0++;
    if (t1 > 0)
        while (t1 < T && (tmeta[t1] & 0xFFFFF) == (tmeta[t1 - 1] & 0xFFFFF)) t1++;
    if (t0 >= t1) return;

    // ---- pipeline prologue: meta tt..tt+3, data tt..tt+1, idx tt+2..tt+3
    int tcA = t0, tcB = min(t0 + 1, T - 1);
    int tc2 = min(t0 + 2, T - 1), tc3 = min(t0 + 3, T - 1);
    int m0 = tmeta[tcA], m1 = tmeta[tcB], m2 = tmeta[tc2], m3 = tmeta[tc3];
    int s2a = ssrc_pad[tc2 * 16 + eh], s2b = ssrc_pad[tc2 * 16 + 8 + eh];
    int s3a = ssrc_pad[tc3 * 16 + eh], s3b = ssrc_pad[tc3 * 16 + 8 + eh];
    int s0a = ssrc_pad[tcA * 16 + eh], s0b = ssrc_pad[tcA * 16 + 8 + eh];
    int s1a = ssrc_pad[tcB * 16 + eh], s1b = ssrc_pad[tcB * 16 + 8 + eh];
    f16x8 ps0a = *(const f16x8a*)&psrc[(long)s0a * 64 + sub * 8];
    f16x8 ps0b = *(const f16x8a*)&psrc[(long)s0b * 64 + sub * 8];
    f16x8 pd0  = *(const f16x8a*)&pdst[(long)(m0 & 0xFFFFF) * 64 + sub * 8];
    f16x8 ps1a = *(const f16x8a*)&psrc[(long)s1a * 64 + sub * 8];
    f16x8 ps1b = *(const f16x8a*)&psrc[(long)s1b * 64 + sub * 8];
    f16x8 pd1  = *(const f16x8a*)&pdst[(long)(m1 & 0xFFFFF) * 64 + sub * 8];

    float accn[4] = {0.f, 0.f, 0.f, 0.f};

    for (int tt = t0; tt < t1; tt += 2) {
        // ---- prefetch meta/indices for tiles tt+4, tt+5 ----
        const int tc4 = min(tt + 4, T - 1), tc5 = min(tt + 5, T - 1);
        int m4 = tmeta[tc4], m5 = tmeta[tc5];
        int s4a = ssrc_pad[tc4 * 16 + eh], s4b = ssrc_pad[tc4 * 16 + 8 + eh];
        int s5a = ssrc_pad[tc5 * 16 + eh], s5b = ssrc_pad[tc5 * 16 + 8 + eh];
        // ---- load gather data for tiles tt+2, tt+3 ----
        f16x8 ps2a = *(const f16x8a*)&psrc[(long)s2a * 64 + sub * 8];
        f16x8 ps2b = *(const f16x8a*)&psrc[(long)s2b * 64 + sub * 8];
        f16x8 pd2  = *(const f16x8a*)&pdst[(long)(m2 & 0xFFFFF) * 64 + sub * 8];
        f16x8 ps3a = *(const f16x8a*)&psrc[(long)s3a * 64 + sub * 8];
        f16x8 ps3b = *(const f16x8a*)&psrc[(long)s3b * 64 + sub * 8];
        f16x8 pd3  = *(const f16x8a*)&pdst[(long)(m3 & 0xFFFFF) * 64 + sub * 8];

        const int hasB = (tt + 1 < t1);
        const int v0 = m0 >> 20;
        const int v1 = hasB ? (m1 >> 20) : 0;

        // ---- layer 0 (both tiles) ----
        *(f16x8a*)&yA[eh * Y_ST + sub * 8]       = relu8(ps0a + pd0);
        *(f16x8a*)&yA[(8 + eh) * Y_ST + sub * 8] = relu8(ps0b + pd0);
        *(f16x8a*)&yB[eh * Y_ST + sub * 8]       = relu8(ps1a + pd1);
        *(f16x8a*)&yB[(8 + eh) * Y_ST + sub * 8] = relu8(ps1b + pd1);

        // ---- layer 1 (both) ----
        f16x8 a1A[2], a1B[2];
#pragma unroll
        for (int c = 0; c < 2; c++) {
            a1A[c] = *(const f16x8a*)&yA[lm * Y_ST + c * 32 + quad * 8];
            a1B[c] = *(const f16x8a*)&yB[lm * Y_ST + c * 32 + quad * 8];
        }
        f32x4 accA[4], accB[4];
#pragma unroll
        for (int q = 0; q < 4; q++) {
            accA[q] = (f32x4){bias1[q], bias1[q], bias1[q], bias1[q]};
            accB[q] = (f32x4){bias1[q], bias1[q], bias1[q], bias1[q]};
        }
#pragma unroll
        for (int c = 0; c < 2; c++)
#pragma unroll
            for (int q = 0; q < 4; q++) {
                accA[q] = __builtin_amdgcn_mfma_f32_16x16x32_f16(a1A[c], bw1[c][q], accA[q], 0, 0, 0);
                accB[q] = __builtin_amdgcn_mfma_f32_16x16x32_f16(a1B[c], bw1[c][q], accB[q], 0, 0, 0);
            }
#pragma unroll
        for (int q = 0; q < 4; q++)
#pragma unroll
            for (int r = 0; r < 4; r++) {
                yA[(quad * 4 + r) * Y_ST + q * 16 + lm] = (f16)fmaxf(accA[q][r], 0.f);
                yB[(quad * 4 + r) * Y_ST + q * 16 + lm] = (f16)fmaxf(accB[q][r], 0.f);
            }

        // ---- layer 2 (both) ----
        f16x8 a2A[2], a2B[2];
#pragma unroll
        for (int c = 0; c < 2; c++) {
            a2A[c] = *(const f16x8a*)&yA[lm * Y_ST + c * 32 + quad * 8];
            a2B[c] = *(const f16x8a*)&yB[lm * Y_ST + c * 32 + quad * 8];
        }
#pragma unroll
        for (int q = 0; q < 4; q++) {
            accA[q] = (f32x4){bias2[q], bias2[q], bias2[q], bias2[q]};
            accB[q] = (f32x4){bias2[q], bias2[q], bias2[q], bias2[q]};
        }
#pragma unroll
        for (int c = 0; c < 2; c++)
#pragma unroll
            for (int q = 0; q < 4; q++) {
                accA[q] = __builtin_amdgcn_mfma_f32_16x16x32_f16(a2A[c], bw2[c][q], accA[q], 0, 0, 0);
                accB[q] = __builtin_amdgcn_mfma_f32_16x16x32_f16(a2B[c], bw2[c][q], accB[q], 0, 0, 0);
            }

        // ---- accumulate + flush tile A (plain store: node owned by wave) ----
#pragma unroll
        for (int q = 0; q < 4; q++)
#pragma unroll
            for (int r = 0; r < 4; r++)
                if (quad * 4 + r < v0) accn[q] += accA[q][r];
        {
            const int curn = m0 & 0xFFFFF;
            const int nxt  = hasB ? (m1 & 0xFFFFF) : -1;
            if (nxt != curn) {
#pragma unroll
                for (int q = 0; q < 4; q++) {
                    float v = accn[q];
                    v += __shfl_xor(v, 16, 64);
                    v += __shfl_xor(v, 32, 64);
                    if (quad == 0) hout[(long)curn * 64 + q * 16 + lm] = v;
                    accn[q] = 0.f;
                }
            }
        }
        // ---- accumulate + flush tile B ----
        if (hasB) {
#pragma unroll
            for (int q = 0; q < 4; q++)
#pragma unroll
                for (int r = 0; r < 4; r++)
                    if (quad * 4 + r < v1) accn[q] += accB[q][r];
            const int curn = m1 & 0xFFFFF;
            const int nxt  = (tt + 2 < t1) ? (m2 & 0xFFFFF) : -1;
            if (nxt != curn) {
#pragma unroll
                for (int q = 0; q < 4; q++) {
                    float v = accn[q];
                    v += __shfl_xor(v, 16, 64);
                    v += __shfl_xor(v, 32, 64);
                    if (quad == 0) hout[(long)curn * 64 + q * 16 + lm] = v;
                    accn[q] = 0.f;
                }
            }
        }

        // ---- rotate pipeline ----
        m0 = m2; m1 = m3; m2 = m4; m3 = m5;
        s2a = s4a; s2b = s4b; s3a = s5a; s3b = s5b;
        ps0a = ps2a; ps0b = ps2b; pd0 = pd2;
        ps1a = ps3a; ps1b = ps3b; pd1 = pd3;
    }
}

__global__ __launch_bounds__(256) void k_lin_out(const int* __restrict__ flags,
                                                 const float* __restrict__ h,
                                                 const void* __restrict__ w,
                                                 const void* __restrict__ b,
                                                 float* __restrict__ out)
{
    int idx = blockIdx.x * 256 + threadIdx.x;
    if (idx >= N_NODES * D_OUT) return;
    const int isbf = flags[0];
    int n = idx >> 4, c = idx & 15;
    float acc = rdf(b, c, isbf);
    const float* hr = h + (long)n * D_HID;
#pragma unroll
    for (int i = 0; i < D_HID; i++) acc += hr[i] * rdf(w, (long)i * D_OUT + c, isbf);
    out[idx] = acc;
}

extern "C" void kernel_launch(void* const* d_in, const int* in_sizes, int n_in,
                              void* d_out, int out_size, void* d_ws, size_t ws_size,
                              hipStream_t stream)
{
    const void* x    = d_in[0];
    const int*  ei   = (const int*)d_in[2];
    const void* liw  = d_in[3];
    const void* lib  = d_in[4];
    const void* w0   = d_in[5];
    const void* b0   = d_in[6];
    const void* w1   = d_in[7];
    const void* b1   = d_in[8];
    const void* w2   = d_in[9];
    const void* b2   = d_in[10];
    const void* low  = d_in[11];
    const void* lob  = d_in[12];
    float* out = (float*)d_out;

    // ws (~37 MB, under proven 38.7 MB)
    char* wp = (char*)d_ws;
    int*   flags  = (int*)wp;                 wp += 256;
    float* hA     = (float*)wp;               wp += (size_t)N_NODES * D_HID * 4;
    f16*   Psrc   = (f16*)wp;                 wp += (size_t)N_NODES * D_HID * 2;
    f16*   Pdst   = (f16*)wp;                 wp += (size_t)N_NODES * D_HID * 2;
    f16*   wfrag  = (f16*)wp;                 wp += (size_t)4 * 32 * 64 * 8 * 2;  // 128 KB
    int*   hist   = (int*)wp;                 wp += (size_t)N_NODES * 4;
    int*   off    = (int*)wp;                 wp += ((size_t)N_NODES + 1) * 4;
    int*   cursor = (int*)wp;                 wp += (size_t)N_NODES * 4;
    int*   toff   = (int*)wp;                 wp += ((size_t)N_NODES + 1) * 4;
    int*   bsum_e = (int*)wp;                 wp += 256 * 4;
    int*   bsum_t = (int*)wp;                 wp += 256 * 4;
    int*   boff_e = (int*)wp;                 wp += 256 * 4;
    int*   boff_t = (int*)wp;                 wp += 256 * 4;
    int*   ssrc   = (int*)wp;                 wp += (size_t)N_EDGES * 4;
    int*   tmeta  = (int*)wp;                 wp += (size_t)TMAX * 4;
    int*   spad   = (int*)wp;                 // TMAX*16 ints = 6.4 MB

    // detect + hist zeroing fused
    k_detect<<<NCHUNK, 256, 0, stream>>>((const unsigned short*)x, ei, flags, hist);
    // fused: wprep (32 blk) + hist4 (GE4 blk) + lin_in (GH blk)
    k_prep<<<32 + GE4 + GH, 256, 0, stream>>>(flags, w0, w1, w2, wfrag,
                                              ei, hist, x, liw, lib, hA);

    k_scan1<<<NCHUNK, 256, 0, stream>>>(hist, bsum_e, bsum_t);
    k_scan2<<<1, 256, 0, stream>>>(bsum_e, bsum_t, boff_e, boff_t,
                                   off + N_NODES, toff + N_NODES);
    k_scan3<<<NCHUNK, 256, 0, stream>>>(hist, boff_e, boff_t, off, cursor, toff, tmeta);
    k_scatter4<<<(N_EDGES / 4 + 255) / 256, 256, 0, stream>>>(flags, ei, cursor, ssrc);
    k_fill<<<(TMAX * 16) / 256, 256, 0, stream>>>(hist, off, toff, toff + N_NODES,
                                                  tmeta, ssrc, spad);

    for (int k = 0; k < 4; k++) {
        k_proj<<<(N_NODES / 16 + 3) / 4, 256, 0, stream>>>(flags, hA, wfrag, b0,
                                                           hist, Psrc, Pdst, k);
        k_edge_tile<<<1024, 256, 0, stream>>>(flags, spad, tmeta, toff,
                                              Psrc, Pdst, hA, wfrag, b1, b2, k);
    }

    k_lin_out<<<(N_NODES * D_OUT + 255) / 256, 256, 0, stream>>>(flags, hA, low, lob, out);
}